// Round 1
// baseline (4459.589 us; speedup 1.0000x reference)
//
#include <hip/hip_runtime.h>

#define N_NODES 50000
#define N_EDGES 800000
#define D 128
#define ND (N_NODES * D)
#define BN_EPS 1e-5f
#define TM 64
#define TN 64

// ---------------------------------------------------------------------------
// Scatter-aggregate: agg[dst] += z[src] * w  (atomicAdd, 32 threads/edge, float4)
// ---------------------------------------------------------------------------
__global__ void scatter_kernel(const float* __restrict__ z, const float* __restrict__ ew,
                               const int* __restrict__ src, const int* __restrict__ dst,
                               float* __restrict__ agg) {
    int tid = blockIdx.x * blockDim.x + threadIdx.x;
    int e = tid >> 5;
    if (e >= N_EDGES) return;
    int f = (tid & 31) << 2;
    int s = src[e], d = dst[e];
    float w = ew[e];
    float4 v = *(const float4*)(z + (size_t)s * D + f);
    float* a = agg + (size_t)d * D + f;
    atomicAdd(a + 0, v.x * w);
    atomicAdd(a + 1, v.y * w);
    atomicAdd(a + 2, v.z * w);
    atomicAdd(a + 3, v.w * w);
}

// ---------------------------------------------------------------------------
// GEMM: out = relu(A @ W + bias), A is [N_NODES x 128], W is [128 x 128].
// PRE: A-row = (1+eps)*Zin + AGG (GIN pre-MLP combine), else A-row = Zin.
// 64x64 tile per block, 256 threads, each thread 4x4 register tile.
// ---------------------------------------------------------------------------
template<bool PRE>
__global__ __launch_bounds__(256, 2) void gemm_relu(
    const float* __restrict__ Zin, const float* __restrict__ AGG,
    const float* __restrict__ epsp, int layer,
    const float* __restrict__ W, const float* __restrict__ bias,
    float* __restrict__ out) {
    __shared__ float As[D][TM + 4];   // A transposed: As[k][r]
    __shared__ float Ws[D][TN + 4];   // Ws[k][c]
    int tid = threadIdx.x;
    int row0 = blockIdx.x * TM;
    int col0 = blockIdx.y * TN;
    float epsv = 0.0f;
    if (PRE) epsv = 1.0f + epsp[layer];

    // load W tile (128 x 64)
    for (int i = tid; i < D * (TN / 4); i += 256) {
        int k = i >> 4;
        int c = (i & 15) << 2;
        float4 w4 = *(const float4*)(W + (size_t)k * D + col0 + c);
        Ws[k][c + 0] = w4.x; Ws[k][c + 1] = w4.y;
        Ws[k][c + 2] = w4.z; Ws[k][c + 3] = w4.w;
    }
    // load A tile (64 rows x 128 k), transposed into As
    for (int i = tid; i < TM * (D / 4); i += 256) {
        int r = i >> 5;
        int k = (i & 31) << 2;
        int gr = row0 + r;
        float4 v = make_float4(0.f, 0.f, 0.f, 0.f);
        if (gr < N_NODES) {
            v = *(const float4*)(Zin + (size_t)gr * D + k);
            if (PRE) {
                float4 a = *(const float4*)(AGG + (size_t)gr * D + k);
                v.x = epsv * v.x + a.x;
                v.y = epsv * v.y + a.y;
                v.z = epsv * v.z + a.z;
                v.w = epsv * v.w + a.w;
            }
        }
        As[k + 0][r] = v.x;
        As[k + 1][r] = v.y;
        As[k + 2][r] = v.z;
        As[k + 3][r] = v.w;
    }
    __syncthreads();

    int colg = tid & 15;   // 16 col groups x 4 cols
    int rowg = tid >> 4;   // 16 row groups x 4 rows
    float acc[4][4] = {};
    #pragma unroll 8
    for (int k = 0; k < D; ++k) {
        float4 a4 = *(const float4*)&As[k][rowg * 4];
        float4 w4 = *(const float4*)&Ws[k][colg * 4];
        acc[0][0] += a4.x * w4.x; acc[0][1] += a4.x * w4.y; acc[0][2] += a4.x * w4.z; acc[0][3] += a4.x * w4.w;
        acc[1][0] += a4.y * w4.x; acc[1][1] += a4.y * w4.y; acc[1][2] += a4.y * w4.z; acc[1][3] += a4.y * w4.w;
        acc[2][0] += a4.z * w4.x; acc[2][1] += a4.z * w4.y; acc[2][2] += a4.z * w4.z; acc[2][3] += a4.z * w4.w;
        acc[3][0] += a4.w * w4.x; acc[3][1] += a4.w * w4.y; acc[3][2] += a4.w * w4.z; acc[3][3] += a4.w * w4.w;
    }

    int cbase = col0 + colg * 4;
    float b0 = bias[cbase + 0], b1 = bias[cbase + 1], b2 = bias[cbase + 2], b3 = bias[cbase + 3];
    #pragma unroll
    for (int r = 0; r < 4; ++r) {
        int gr = row0 + rowg * 4 + r;
        if (gr < N_NODES) {
            float4 o;
            o.x = fmaxf(acc[r][0] + b0, 0.f);
            o.y = fmaxf(acc[r][1] + b1, 0.f);
            o.z = fmaxf(acc[r][2] + b2, 0.f);
            o.w = fmaxf(acc[r][3] + b3, 0.f);
            *(float4*)(out + (size_t)gr * D + cbase) = o;
        }
    }
}

// ---------------------------------------------------------------------------
// BatchNorm statistics: per-column sum and sum-of-squares into stats[0..255]
// ---------------------------------------------------------------------------
__global__ void bn_stats(const float* __restrict__ Z, float* __restrict__ stats) {
    __shared__ float red[256];
    int col = threadIdx.x & 127;
    int half = threadIdx.x >> 7;
    float s = 0.f, s2 = 0.f;
    for (int r = blockIdx.x * 2 + half; r < N_NODES; r += gridDim.x * 2) {
        float v = Z[(size_t)r * D + col];
        s += v;
        s2 += v * v;
    }
    red[threadIdx.x] = s;
    __syncthreads();
    if (half == 0) atomicAdd(&stats[col], s + red[threadIdx.x + 128]);
    __syncthreads();
    red[threadIdx.x] = s2;
    __syncthreads();
    if (half == 0) atomicAdd(&stats[D + col], s2 + red[threadIdx.x + 128]);
}

// ---------------------------------------------------------------------------
// Final: zn = BN(Z)*gamma+beta (written to zn_out), p = PReLU(zn @ Wp + bp)
// ---------------------------------------------------------------------------
__global__ __launch_bounds__(256, 2) void bn_proj(
    const float* __restrict__ Z, const float* __restrict__ stats,
    const float* __restrict__ gamma, const float* __restrict__ beta,
    const float* __restrict__ Wp, const float* __restrict__ bp,
    const float* __restrict__ prelu_a,
    float* __restrict__ zn_out, float* __restrict__ p_out) {
    __shared__ float As[D][TM + 4];
    __shared__ float Ws[D][TN + 4];
    __shared__ float scale_s[D];
    __shared__ float shift_s[D];
    int tid = threadIdx.x;
    int row0 = blockIdx.x * TM;
    int col0 = blockIdx.y * TN;

    if (tid < D) {
        float m = stats[tid] * (1.0f / N_NODES);
        float v = stats[D + tid] * (1.0f / N_NODES) - m * m;
        float rs = rsqrtf(v + BN_EPS);
        float sc = rs * gamma[tid];
        scale_s[tid] = sc;
        shift_s[tid] = beta[tid] - m * sc;
    }
    __syncthreads();

    for (int i = tid; i < D * (TN / 4); i += 256) {
        int k = i >> 4;
        int c = (i & 15) << 2;
        float4 w4 = *(const float4*)(Wp + (size_t)k * D + col0 + c);
        Ws[k][c + 0] = w4.x; Ws[k][c + 1] = w4.y;
        Ws[k][c + 2] = w4.z; Ws[k][c + 3] = w4.w;
    }
    for (int i = tid; i < TM * (D / 4); i += 256) {
        int r = i >> 5;
        int k = (i & 31) << 2;
        int gr = row0 + r;
        float4 v = make_float4(0.f, 0.f, 0.f, 0.f);
        if (gr < N_NODES) {
            v = *(const float4*)(Z + (size_t)gr * D + k);
            v.x = v.x * scale_s[k + 0] + shift_s[k + 0];
            v.y = v.y * scale_s[k + 1] + shift_s[k + 1];
            v.z = v.z * scale_s[k + 2] + shift_s[k + 2];
            v.w = v.w * scale_s[k + 3] + shift_s[k + 3];
            if (blockIdx.y == 0) {
                *(float4*)(zn_out + (size_t)gr * D + k) = v;
            }
        }
        As[k + 0][r] = v.x;
        As[k + 1][r] = v.y;
        As[k + 2][r] = v.z;
        As[k + 3][r] = v.w;
    }
    __syncthreads();

    int colg = tid & 15;
    int rowg = tid >> 4;
    float acc[4][4] = {};
    #pragma unroll 8
    for (int k = 0; k < D; ++k) {
        float4 a4 = *(const float4*)&As[k][rowg * 4];
        float4 w4 = *(const float4*)&Ws[k][colg * 4];
        acc[0][0] += a4.x * w4.x; acc[0][1] += a4.x * w4.y; acc[0][2] += a4.x * w4.z; acc[0][3] += a4.x * w4.w;
        acc[1][0] += a4.y * w4.x; acc[1][1] += a4.y * w4.y; acc[1][2] += a4.y * w4.z; acc[1][3] += a4.y * w4.w;
        acc[2][0] += a4.z * w4.x; acc[2][1] += a4.z * w4.y; acc[2][2] += a4.z * w4.z; acc[2][3] += a4.z * w4.w;
        acc[3][0] += a4.w * w4.x; acc[3][1] += a4.w * w4.y; acc[3][2] += a4.w * w4.z; acc[3][3] += a4.w * w4.w;
    }

    float a = prelu_a[0];
    int cbase = col0 + colg * 4;
    float b0 = bp[cbase + 0], b1 = bp[cbase + 1], b2 = bp[cbase + 2], b3 = bp[cbase + 3];
    #pragma unroll
    for (int r = 0; r < 4; ++r) {
        int gr = row0 + rowg * 4 + r;
        if (gr < N_NODES) {
            float4 o;
            o.x = acc[r][0] + b0;
            o.y = acc[r][1] + b1;
            o.z = acc[r][2] + b2;
            o.w = acc[r][3] + b3;
            o.x = (o.x >= 0.f) ? o.x : a * o.x;
            o.y = (o.y >= 0.f) ? o.y : a * o.y;
            o.z = (o.z >= 0.f) ? o.z : a * o.z;
            o.w = (o.w >= 0.f) ? o.w : a * o.w;
            *(float4*)(p_out + (size_t)gr * D + cbase) = o;
        }
    }
}

// ---------------------------------------------------------------------------
extern "C" void kernel_launch(void* const* d_in, const int* in_sizes, int n_in,
                              void* d_out, int out_size, void* d_ws, size_t ws_size,
                              hipStream_t stream) {
    (void)in_sizes; (void)n_in; (void)out_size; (void)ws_size;
    const float* x     = (const float*)d_in[0];
    const float* ew    = (const float*)d_in[1];
    const float* W1s   = (const float*)d_in[2];
    const float* b1s   = (const float*)d_in[3];
    const float* W2s   = (const float*)d_in[4];
    const float* b2s   = (const float*)d_in[5];
    const float* eps   = (const float*)d_in[6];
    const float* gamma = (const float*)d_in[7];
    const float* beta  = (const float*)d_in[8];
    const float* Wp    = (const float*)d_in[9];
    const float* bp    = (const float*)d_in[10];
    const float* pa    = (const float*)d_in[11];
    const int*   ei    = (const int*)d_in[12];
    const int* srcp = ei;
    const int* dstp = ei + N_EDGES;

    float* wsf   = (float*)d_ws;
    float* stats = wsf;          // 256 floats
    float* A     = wsf + 256;    // ND floats (aggregation)
    float* H     = A + ND;       // ND floats (hidden)
    float* Z     = H + ND;       // ND floats (layer output)

    float* out_zn = (float*)d_out;
    float* out_p  = out_zn + ND;

    hipMemsetAsync(stats, 0, 256 * sizeof(float), stream);

    dim3 ggrid((N_NODES + TM - 1) / TM, 2);
    const float* zin = x;
    for (int l = 0; l < 3; ++l) {
        hipMemsetAsync(A, 0, (size_t)ND * sizeof(float), stream);
        int sthreads = N_EDGES * 32;
        scatter_kernel<<<(sthreads + 255) / 256, 256, 0, stream>>>(zin, ew, srcp, dstp, A);
        gemm_relu<true><<<ggrid, 256, 0, stream>>>(zin, A, eps, l, W1s + (size_t)l * D * D, b1s + (size_t)l * D, H);
        gemm_relu<false><<<ggrid, 256, 0, stream>>>(H, nullptr, eps, l, W2s + (size_t)l * D * D, b2s + (size_t)l * D, Z);
        zin = Z;
    }
    bn_stats<<<512, 256, 0, stream>>>(Z, stats);
    bn_proj<<<ggrid, 256, 0, stream>>>(Z, stats, gamma, beta, Wp, bp, pa, out_zn, out_p);
}

// Round 2
// 762.910 us; speedup vs baseline: 5.8455x; 5.8455x over previous
//
#include <hip/hip_runtime.h>

#define N_NODES 50000
#define N_EDGES 800000
#define D 128
#define ND (N_NODES * D)
#define BN_EPS 1e-5f
#define TM 64
#define TN 64

// ---------------------------------------------------------------------------
// CSR build step 1: histogram of dst into offs[1..N]
// ---------------------------------------------------------------------------
__global__ void hist_kernel(const int* __restrict__ dst, int* __restrict__ offs) {
    int e = blockIdx.x * blockDim.x + threadIdx.x;
    if (e < N_EDGES) atomicAdd(&offs[dst[e] + 1], 1);
}

// ---------------------------------------------------------------------------
// CSR build step 2: in-place inclusive scan over offs[1..N] (single block).
// offs[0] stays 0 (memset). 1024 threads, 16 waves, shfl-scan + LDS carry.
// ---------------------------------------------------------------------------
__global__ void scan_kernel(int* __restrict__ offs) {
    __shared__ int wsum[16];
    __shared__ int carry_s;
    int tid = threadIdx.x;
    int lane = tid & 63;
    int wave = tid >> 6;
    if (tid == 0) carry_s = 0;
    __syncthreads();
    for (int base = 1; base <= N_NODES; base += 1024) {
        int idx = base + tid;
        int v = (idx <= N_NODES) ? offs[idx] : 0;
        int x = v;
        #pragma unroll
        for (int d = 1; d < 64; d <<= 1) {
            int y = __shfl_up(x, d, 64);
            if (lane >= d) x += y;
        }
        if (lane == 63) wsum[wave] = x;
        __syncthreads();
        if (wave == 0 && lane < 16) {
            int y = wsum[lane];
            #pragma unroll
            for (int d = 1; d < 16; d <<= 1) {
                int t = __shfl_up(y, d, 64);
                if (lane >= d) y += t;
            }
            wsum[lane] = y;
        }
        __syncthreads();
        int waveoff = (wave > 0) ? wsum[wave - 1] : 0;
        int total = wsum[15];
        int out = x + waveoff + carry_s;
        if (idx <= N_NODES) offs[idx] = out;
        __syncthreads();
        if (tid == 0) carry_s += total;
        __syncthreads();
    }
}

// ---------------------------------------------------------------------------
// CSR build step 3: cursor = offs[0..N-1]
// ---------------------------------------------------------------------------
__global__ void cursor_kernel(const int* __restrict__ offs, int* __restrict__ cursor) {
    int i = blockIdx.x * blockDim.x + threadIdx.x;
    if (i < N_NODES) cursor[i] = offs[i];
}

// ---------------------------------------------------------------------------
// CSR build step 4: bucket-fill sorted src + weight by dst
// ---------------------------------------------------------------------------
__global__ void fill_kernel(const int* __restrict__ src, const int* __restrict__ dst,
                            const float* __restrict__ ew,
                            int* __restrict__ cursor, int* __restrict__ ssrc,
                            float* __restrict__ sw) {
    int e = blockIdx.x * blockDim.x + threadIdx.x;
    if (e < N_EDGES) {
        int d = dst[e];
        int p = atomicAdd(&cursor[d], 1);
        ssrc[p] = src[e];
        sw[p] = ew[e];
    }
}

// ---------------------------------------------------------------------------
// Gather-aggregate + GIN combine: out[n] = (1+eps)*z[n] + sum_j w_j * z[src_j]
// 32 lanes per node, each lane owns a float4 feature chunk.
// ---------------------------------------------------------------------------
__global__ void gather_agg(const float* __restrict__ z, const int* __restrict__ offs,
                           const int* __restrict__ ssrc, const float* __restrict__ sw,
                           const float* __restrict__ epsp, int layer,
                           float* __restrict__ out) {
    int tid = blockIdx.x * blockDim.x + threadIdx.x;
    int n = tid >> 5;
    if (n >= N_NODES) return;
    int f = (tid & 31) << 2;
    float epsv = 1.0f + epsp[layer];
    int beg = offs[n], end = offs[n + 1];
    float4 zi = *(const float4*)(z + (size_t)n * D + f);
    float4 acc;
    acc.x = epsv * zi.x; acc.y = epsv * zi.y;
    acc.z = epsv * zi.z; acc.w = epsv * zi.w;
    for (int j = beg; j < end; ++j) {
        int s = ssrc[j];
        float w = sw[j];
        float4 v = *(const float4*)(z + (size_t)s * D + f);
        acc.x += v.x * w; acc.y += v.y * w;
        acc.z += v.z * w; acc.w += v.w * w;
    }
    *(float4*)(out + (size_t)n * D + f) = acc;
}

// ---------------------------------------------------------------------------
// GEMM: out = relu(A @ W + bias), A is [N_NODES x 128], W is [128 x 128].
// 64x64 tile per block, 256 threads, each thread 4x4 register tile.
// ---------------------------------------------------------------------------
__global__ __launch_bounds__(256, 2) void gemm_relu(
    const float* __restrict__ A_in,
    const float* __restrict__ W, const float* __restrict__ bias,
    float* __restrict__ out) {
    __shared__ float As[D][TM + 4];   // A transposed: As[k][r]
    __shared__ float Ws[D][TN + 4];   // Ws[k][c]
    int tid = threadIdx.x;
    int row0 = blockIdx.x * TM;
    int col0 = blockIdx.y * TN;

    for (int i = tid; i < D * (TN / 4); i += 256) {
        int k = i >> 4;
        int c = (i & 15) << 2;
        float4 w4 = *(const float4*)(W + (size_t)k * D + col0 + c);
        Ws[k][c + 0] = w4.x; Ws[k][c + 1] = w4.y;
        Ws[k][c + 2] = w4.z; Ws[k][c + 3] = w4.w;
    }
    for (int i = tid; i < TM * (D / 4); i += 256) {
        int r = i >> 5;
        int k = (i & 31) << 2;
        int gr = row0 + r;
        float4 v = make_float4(0.f, 0.f, 0.f, 0.f);
        if (gr < N_NODES) v = *(const float4*)(A_in + (size_t)gr * D + k);
        As[k + 0][r] = v.x;
        As[k + 1][r] = v.y;
        As[k + 2][r] = v.z;
        As[k + 3][r] = v.w;
    }
    __syncthreads();

    int colg = tid & 15;
    int rowg = tid >> 4;
    float acc[4][4] = {};
    #pragma unroll 8
    for (int k = 0; k < D; ++k) {
        float4 a4 = *(const float4*)&As[k][rowg * 4];
        float4 w4 = *(const float4*)&Ws[k][colg * 4];
        acc[0][0] += a4.x * w4.x; acc[0][1] += a4.x * w4.y; acc[0][2] += a4.x * w4.z; acc[0][3] += a4.x * w4.w;
        acc[1][0] += a4.y * w4.x; acc[1][1] += a4.y * w4.y; acc[1][2] += a4.y * w4.z; acc[1][3] += a4.y * w4.w;
        acc[2][0] += a4.z * w4.x; acc[2][1] += a4.z * w4.y; acc[2][2] += a4.z * w4.z; acc[2][3] += a4.z * w4.w;
        acc[3][0] += a4.w * w4.x; acc[3][1] += a4.w * w4.y; acc[3][2] += a4.w * w4.z; acc[3][3] += a4.w * w4.w;
    }

    int cbase = col0 + colg * 4;
    float b0 = bias[cbase + 0], b1 = bias[cbase + 1], b2 = bias[cbase + 2], b3 = bias[cbase + 3];
    #pragma unroll
    for (int r = 0; r < 4; ++r) {
        int gr = row0 + rowg * 4 + r;
        if (gr < N_NODES) {
            float4 o;
            o.x = fmaxf(acc[r][0] + b0, 0.f);
            o.y = fmaxf(acc[r][1] + b1, 0.f);
            o.z = fmaxf(acc[r][2] + b2, 0.f);
            o.w = fmaxf(acc[r][3] + b3, 0.f);
            *(float4*)(out + (size_t)gr * D + cbase) = o;
        }
    }
}

// ---------------------------------------------------------------------------
// BatchNorm statistics: per-column sum and sum-of-squares into stats[0..255]
// ---------------------------------------------------------------------------
__global__ void bn_stats(const float* __restrict__ Z, float* __restrict__ stats) {
    __shared__ float red[256];
    int col = threadIdx.x & 127;
    int half = threadIdx.x >> 7;
    float s = 0.f, s2 = 0.f;
    for (int r = blockIdx.x * 2 + half; r < N_NODES; r += gridDim.x * 2) {
        float v = Z[(size_t)r * D + col];
        s += v;
        s2 += v * v;
    }
    red[threadIdx.x] = s;
    __syncthreads();
    if (half == 0) atomicAdd(&stats[col], s + red[threadIdx.x + 128]);
    __syncthreads();
    red[threadIdx.x] = s2;
    __syncthreads();
    if (half == 0) atomicAdd(&stats[D + col], s2 + red[threadIdx.x + 128]);
}

// ---------------------------------------------------------------------------
// Final: zn = BN(Z)*gamma+beta (written to zn_out), p = PReLU(zn @ Wp + bp)
// ---------------------------------------------------------------------------
__global__ __launch_bounds__(256, 2) void bn_proj(
    const float* __restrict__ Z, const float* __restrict__ stats,
    const float* __restrict__ gamma, const float* __restrict__ beta,
    const float* __restrict__ Wp, const float* __restrict__ bp,
    const float* __restrict__ prelu_a,
    float* __restrict__ zn_out, float* __restrict__ p_out) {
    __shared__ float As[D][TM + 4];
    __shared__ float Ws[D][TN + 4];
    __shared__ float scale_s[D];
    __shared__ float shift_s[D];
    int tid = threadIdx.x;
    int row0 = blockIdx.x * TM;
    int col0 = blockIdx.y * TN;

    if (tid < D) {
        float m = stats[tid] * (1.0f / N_NODES);
        float v = stats[D + tid] * (1.0f / N_NODES) - m * m;
        float rs = rsqrtf(v + BN_EPS);
        float sc = rs * gamma[tid];
        scale_s[tid] = sc;
        shift_s[tid] = beta[tid] - m * sc;
    }
    __syncthreads();

    for (int i = tid; i < D * (TN / 4); i += 256) {
        int k = i >> 4;
        int c = (i & 15) << 2;
        float4 w4 = *(const float4*)(Wp + (size_t)k * D + col0 + c);
        Ws[k][c + 0] = w4.x; Ws[k][c + 1] = w4.y;
        Ws[k][c + 2] = w4.z; Ws[k][c + 3] = w4.w;
    }
    for (int i = tid; i < TM * (D / 4); i += 256) {
        int r = i >> 5;
        int k = (i & 31) << 2;
        int gr = row0 + r;
        float4 v = make_float4(0.f, 0.f, 0.f, 0.f);
        if (gr < N_NODES) {
            v = *(const float4*)(Z + (size_t)gr * D + k);
            v.x = v.x * scale_s[k + 0] + shift_s[k + 0];
            v.y = v.y * scale_s[k + 1] + shift_s[k + 1];
            v.z = v.z * scale_s[k + 2] + shift_s[k + 2];
            v.w = v.w * scale_s[k + 3] + shift_s[k + 3];
            if (blockIdx.y == 0) {
                *(float4*)(zn_out + (size_t)gr * D + k) = v;
            }
        }
        As[k + 0][r] = v.x;
        As[k + 1][r] = v.y;
        As[k + 2][r] = v.z;
        As[k + 3][r] = v.w;
    }
    __syncthreads();

    int colg = tid & 15;
    int rowg = tid >> 4;
    float acc[4][4] = {};
    #pragma unroll 8
    for (int k = 0; k < D; ++k) {
        float4 a4 = *(const float4*)&As[k][rowg * 4];
        float4 w4 = *(const float4*)&Ws[k][colg * 4];
        acc[0][0] += a4.x * w4.x; acc[0][1] += a4.x * w4.y; acc[0][2] += a4.x * w4.z; acc[0][3] += a4.x * w4.w;
        acc[1][0] += a4.y * w4.x; acc[1][1] += a4.y * w4.y; acc[1][2] += a4.y * w4.z; acc[1][3] += a4.y * w4.w;
        acc[2][0] += a4.z * w4.x; acc[2][1] += a4.z * w4.y; acc[2][2] += a4.z * w4.z; acc[2][3] += a4.z * w4.w;
        acc[3][0] += a4.w * w4.x; acc[3][1] += a4.w * w4.y; acc[3][2] += a4.w * w4.z; acc[3][3] += a4.w * w4.w;
    }

    float a = prelu_a[0];
    int cbase = col0 + colg * 4;
    float b0 = bp[cbase + 0], b1 = bp[cbase + 1], b2 = bp[cbase + 2], b3 = bp[cbase + 3];
    #pragma unroll
    for (int r = 0; r < 4; ++r) {
        int gr = row0 + rowg * 4 + r;
        if (gr < N_NODES) {
            float4 o;
            o.x = acc[r][0] + b0;
            o.y = acc[r][1] + b1;
            o.z = acc[r][2] + b2;
            o.w = acc[r][3] + b3;
            o.x = (o.x >= 0.f) ? o.x : a * o.x;
            o.y = (o.y >= 0.f) ? o.y : a * o.y;
            o.z = (o.z >= 0.f) ? o.z : a * o.z;
            o.w = (o.w >= 0.f) ? o.w : a * o.w;
            *(float4*)(p_out + (size_t)gr * D + cbase) = o;
        }
    }
}

// ---------------------------------------------------------------------------
extern "C" void kernel_launch(void* const* d_in, const int* in_sizes, int n_in,
                              void* d_out, int out_size, void* d_ws, size_t ws_size,
                              hipStream_t stream) {
    (void)in_sizes; (void)n_in; (void)out_size; (void)ws_size;
    const float* x     = (const float*)d_in[0];
    const float* ew    = (const float*)d_in[1];
    const float* W1s   = (const float*)d_in[2];
    const float* b1s   = (const float*)d_in[3];
    const float* W2s   = (const float*)d_in[4];
    const float* b2s   = (const float*)d_in[5];
    const float* eps   = (const float*)d_in[6];
    const float* gamma = (const float*)d_in[7];
    const float* beta  = (const float*)d_in[8];
    const float* Wp    = (const float*)d_in[9];
    const float* bp    = (const float*)d_in[10];
    const float* pa    = (const float*)d_in[11];
    const int*   ei    = (const int*)d_in[12];
    const int* srcp = ei;
    const int* dstp = ei + N_EDGES;

    // workspace layout (floats): stats 256 | offs 50004 | cursor 50004 |
    //                            ssrc 800000 | sw 800000 | A ND | H ND | Z ND
    float* wsf    = (float*)d_ws;
    float* stats  = wsf;                      // 256 floats
    int*   offs   = (int*)(stats + 256);      // N_NODES+1 (padded to 50004)
    int*   cursor = offs + 50004;             // N_NODES (padded to 50004)
    int*   ssrc   = cursor + 50004;           // N_EDGES
    float* sw     = (float*)(ssrc + N_EDGES); // N_EDGES
    float* A      = sw + N_EDGES;             // ND
    float* H      = A + ND;                   // ND
    float* Z      = H + ND;                   // ND

    float* out_zn = (float*)d_out;
    float* out_p  = out_zn + ND;

    hipMemsetAsync(stats, 0, 256 * sizeof(float), stream);
    hipMemsetAsync(offs, 0, (N_NODES + 1) * sizeof(int), stream);

    // --- CSR build (once per call) ---
    hist_kernel<<<(N_EDGES + 255) / 256, 256, 0, stream>>>(dstp, offs);
    scan_kernel<<<1, 1024, 0, stream>>>(offs);
    cursor_kernel<<<(N_NODES + 255) / 256, 256, 0, stream>>>(offs, cursor);
    fill_kernel<<<(N_EDGES + 255) / 256, 256, 0, stream>>>(srcp, dstp, ew, cursor, ssrc, sw);

    dim3 ggrid((N_NODES + TM - 1) / TM, 2);
    int agg_threads = N_NODES * 32;
    const float* zin = x;
    for (int l = 0; l < 3; ++l) {
        gather_agg<<<(agg_threads + 255) / 256, 256, 0, stream>>>(zin, offs, ssrc, sw, eps, l, A);
        gemm_relu<<<ggrid, 256, 0, stream>>>(A, W1s + (size_t)l * D * D, b1s + (size_t)l * D, H);
        gemm_relu<<<ggrid, 256, 0, stream>>>(H, W2s + (size_t)l * D * D, b2s + (size_t)l * D, Z);
        zin = Z;
    }
    bn_stats<<<512, 256, 0, stream>>>(Z, stats);
    bn_proj<<<ggrid, 256, 0, stream>>>(Z, stats, gamma, beta, Wp, bp, pa, out_zn, out_p);
}

// Round 4
// 618.584 us; speedup vs baseline: 7.2094x; 1.2333x over previous
//
#include <hip/hip_runtime.h>

#define N_NODES 50000
#define N_EDGES 800000
#define D 128
#define ND (N_NODES * D)
#define BN_EPS 1e-5f
#define TM 64
#define TN 64

typedef short bf16x8 __attribute__((ext_vector_type(8)));
typedef float f32x4 __attribute__((ext_vector_type(4)));

__device__ inline unsigned short f2bf(float f) {
    unsigned int u = __float_as_uint(f);
    u += 0x7FFF + ((u >> 16) & 1);
    return (unsigned short)(u >> 16);
}
__device__ inline float bf2f(unsigned short h) {
    return __uint_as_float(((unsigned int)h) << 16);
}

// ---------------------------------------------------------------------------
// Pack 7 weight matrices [128x128] fp32 into split-bf16 MFMA B-fragment pairs.
// hi at (2m)*16384 + p, lo at (2m+1)*16384 + p where
// p = c*2048 + kc*512 + lane*8 + j holds W[kc*32+(lane>>4)*8+j][c*16+(lane&15)]
// matrices: 0-2 = W1s, 3-5 = W2s, 6 = Wp
// ---------------------------------------------------------------------------
__global__ void pack_w_split(const float* __restrict__ W1s, const float* __restrict__ W2s,
                             const float* __restrict__ Wp, ushort* __restrict__ out) {
    int idx = blockIdx.x * blockDim.x + threadIdx.x;
    if (idx >= 7 * 16384) return;
    int m = idx >> 14;
    int p = idx & 16383;
    int c = p >> 11;
    int kc = (p >> 9) & 3;
    int lane = (p >> 3) & 63;
    int j = p & 7;
    int k = kc * 32 + (lane >> 4) * 8 + j;
    int col = c * 16 + (lane & 15);
    const float* src = (m < 3) ? (W1s + (size_t)m * 16384)
                     : (m < 6) ? (W2s + (size_t)(m - 3) * 16384)
                               : Wp;
    float v = src[k * 128 + col];
    unsigned short hi = f2bf(v);
    float r = v - bf2f(hi);
    out[(size_t)(2 * m) * 16384 + p] = hi;
    out[(size_t)(2 * m + 1) * 16384 + p] = f2bf(r);
}

// ---------------------------------------------------------------------------
// CSR build (identical to the passing round-2 version)
// ---------------------------------------------------------------------------
__global__ void hist_kernel(const int* __restrict__ dst, int* __restrict__ offs) {
    int e = blockIdx.x * blockDim.x + threadIdx.x;
    if (e < N_EDGES) atomicAdd(&offs[dst[e] + 1], 1);
}

__global__ void scan_kernel(int* __restrict__ offs) {
    __shared__ int wsum[16];
    __shared__ int carry_s;
    int tid = threadIdx.x;
    int lane = tid & 63;
    int wave = tid >> 6;
    if (tid == 0) carry_s = 0;
    __syncthreads();
    for (int base = 1; base <= N_NODES; base += 1024) {
        int idx = base + tid;
        int v = (idx <= N_NODES) ? offs[idx] : 0;
        int x = v;
        #pragma unroll
        for (int d = 1; d < 64; d <<= 1) {
            int y = __shfl_up(x, d, 64);
            if (lane >= d) x += y;
        }
        if (lane == 63) wsum[wave] = x;
        __syncthreads();
        if (wave == 0 && lane < 16) {
            int y = wsum[lane];
            #pragma unroll
            for (int d = 1; d < 16; d <<= 1) {
                int t = __shfl_up(y, d, 64);
                if (lane >= d) y += t;
            }
            wsum[lane] = y;
        }
        __syncthreads();
        int waveoff = (wave > 0) ? wsum[wave - 1] : 0;
        int total = wsum[15];
        int out = x + waveoff + carry_s;
        if (idx <= N_NODES) offs[idx] = out;
        __syncthreads();
        if (tid == 0) carry_s += total;
        __syncthreads();
    }
}

__global__ void cursor_kernel(const int* __restrict__ offs, int* __restrict__ cursor) {
    int i = blockIdx.x * blockDim.x + threadIdx.x;
    if (i < N_NODES) cursor[i] = offs[i];
}

__global__ void fill_kernel(const int* __restrict__ src, const int* __restrict__ dst,
                            const float* __restrict__ ew,
                            int* __restrict__ cursor, int* __restrict__ ssrc,
                            float* __restrict__ sw) {
    int e = blockIdx.x * blockDim.x + threadIdx.x;
    if (e < N_EDGES) {
        int d = dst[e];
        int p = atomicAdd(&cursor[d], 1);
        ssrc[p] = src[e];
        sw[p] = ew[e];
    }
}

// ---------------------------------------------------------------------------
// Gather-aggregate + GIN combine (fp32, identical to round 2)
// ---------------------------------------------------------------------------
__global__ void gather_agg(const float* __restrict__ z, const int* __restrict__ offs,
                           const int* __restrict__ ssrc, const float* __restrict__ sw,
                           const float* __restrict__ epsp, int layer,
                           float* __restrict__ out) {
    int tid = blockIdx.x * blockDim.x + threadIdx.x;
    int n = tid >> 5;
    if (n >= N_NODES) return;
    int f = (tid & 31) << 2;
    float epsv = 1.0f + epsp[layer];
    int beg = offs[n], end = offs[n + 1];
    float4 zi = *(const float4*)(z + (size_t)n * D + f);
    float4 acc;
    acc.x = epsv * zi.x; acc.y = epsv * zi.y;
    acc.z = epsv * zi.z; acc.w = epsv * zi.w;
    for (int j = beg; j < end; ++j) {
        int s = ssrc[j];
        float w = sw[j];
        float4 v = *(const float4*)(z + (size_t)s * D + f);
        acc.x += v.x * w; acc.y += v.y * w;
        acc.z += v.z * w; acc.w += v.w * w;
    }
    *(float4*)(out + (size_t)n * D + f) = acc;
}

// ---------------------------------------------------------------------------
// Fused GIN MLP, split-bf16 MFMA (fp32 in/out, ~fp32 accuracy):
// Z = relu(relu(A@W1+b1)@W2+b2)
// 256 threads = 4 waves; each wave computes 16 rows x 128 cols.
// A@W == Ahi@Whi + Alo@Whi + Ahi@Wlo (lo*lo dropped, ~1e-5 rel)
// ---------------------------------------------------------------------------
#define HSTR 132   // floats: 128 + 4 pad
__global__ __launch_bounds__(256) void mlp_fused(
    const float* __restrict__ A,
    const ushort* __restrict__ W1hi, const ushort* __restrict__ W1lo,
    const float* __restrict__ b1,
    const ushort* __restrict__ W2hi, const ushort* __restrict__ W2lo,
    const float* __restrict__ b2, float* __restrict__ Z) {
    __shared__ float Hs[4][16 * HSTR];
    int tid = threadIdx.x;
    int lane = tid & 63;
    int wave = tid >> 6;
    int rlo = lane & 15;
    int quad = lane >> 4;
    int row0 = blockIdx.x * 64 + wave * 16;
    int arow = row0 + rlo;
    int ar = (arow < N_NODES) ? arow : (N_NODES - 1);

    const bf16x8* W1h = (const bf16x8*)W1hi;
    const bf16x8* W1l = (const bf16x8*)W1lo;
    const bf16x8* W2h = (const bf16x8*)W2hi;
    const bf16x8* W2l = (const bf16x8*)W2lo;

    // A fragments (split): lane holds A[ar][kc*32 + quad*8 + j]
    bf16x8 ahi[4], alo[4];
    #pragma unroll
    for (int kc = 0; kc < 4; ++kc) {
        const float* p = A + (size_t)ar * D + kc * 32 + quad * 8;
        float4 v0 = *(const float4*)p;
        float4 v1 = *(const float4*)(p + 4);
        float vv[8] = {v0.x, v0.y, v0.z, v0.w, v1.x, v1.y, v1.z, v1.w};
        #pragma unroll
        for (int j = 0; j < 8; ++j) {
            unsigned short h = f2bf(vv[j]);
            ahi[kc][j] = (short)h;
            alo[kc][j] = (short)f2bf(vv[j] - bf2f(h));
        }
    }

    // GEMM1 (3-term split)
    f32x4 acc[8];
    #pragma unroll
    for (int c = 0; c < 8; ++c) acc[c] = (f32x4){0.f, 0.f, 0.f, 0.f};
    #pragma unroll
    for (int c = 0; c < 8; ++c) {
        #pragma unroll
        for (int kc = 0; kc < 4; ++kc) {
            bf16x8 wh = W1h[(c * 4 + kc) * 64 + lane];
            bf16x8 wl = W1l[(c * 4 + kc) * 64 + lane];
            acc[c] = __builtin_amdgcn_mfma_f32_16x16x32_bf16(alo[kc], wh, acc[c], 0, 0, 0);
            acc[c] = __builtin_amdgcn_mfma_f32_16x16x32_bf16(ahi[kc], wl, acc[c], 0, 0, 0);
            acc[c] = __builtin_amdgcn_mfma_f32_16x16x32_bf16(ahi[kc], wh, acc[c], 0, 0, 0);
        }
    }

    // epilogue 1: relu(acc + b1) -> LDS fp32 (C layout: row=quad*4+r, col=c*16+rlo)
    #pragma unroll
    for (int c = 0; c < 8; ++c) {
        int col = c * 16 + rlo;
        float bb = b1[col];
        #pragma unroll
        for (int r = 0; r < 4; ++r) {
            Hs[wave][(quad * 4 + r) * HSTR + col] = fmaxf(acc[c][r] + bb, 0.f);
        }
    }
    __syncthreads();

    // A2 fragments from LDS (split)
    bf16x8 a2hi[4], a2lo[4];
    #pragma unroll
    for (int kc = 0; kc < 4; ++kc) {
        const float* p = &Hs[wave][rlo * HSTR + kc * 32 + quad * 8];
        #pragma unroll
        for (int j = 0; j < 8; ++j) {
            float v = p[j];
            unsigned short h = f2bf(v);
            a2hi[kc][j] = (short)h;
            a2lo[kc][j] = (short)f2bf(v - bf2f(h));
        }
    }

    // GEMM2 (3-term split)
    f32x4 acc2[8];
    #pragma unroll
    for (int c = 0; c < 8; ++c) acc2[c] = (f32x4){0.f, 0.f, 0.f, 0.f};
    #pragma unroll
    for (int c = 0; c < 8; ++c) {
        #pragma unroll
        for (int kc = 0; kc < 4; ++kc) {
            bf16x8 wh = W2h[(c * 4 + kc) * 64 + lane];
            bf16x8 wl = W2l[(c * 4 + kc) * 64 + lane];
            acc2[c] = __builtin_amdgcn_mfma_f32_16x16x32_bf16(a2lo[kc], wh, acc2[c], 0, 0, 0);
            acc2[c] = __builtin_amdgcn_mfma_f32_16x16x32_bf16(a2hi[kc], wl, acc2[c], 0, 0, 0);
            acc2[c] = __builtin_amdgcn_mfma_f32_16x16x32_bf16(a2hi[kc], wh, acc2[c], 0, 0, 0);
        }
    }

    __syncthreads();
    // epilogue 2: relu(acc2 + b2) -> LDS, then coalesced row-major copy-out
    #pragma unroll
    for (int c = 0; c < 8; ++c) {
        int col = c * 16 + rlo;
        float bb = b2[col];
        #pragma unroll
        for (int r = 0; r < 4; ++r) {
            Hs[wave][(quad * 4 + r) * HSTR + col] = fmaxf(acc2[c][r] + bb, 0.f);
        }
    }
    __syncthreads();
    #pragma unroll
    for (int p2 = 0; p2 < 8; ++p2) {
        int r = p2 * 2 + (lane >> 5);
        int grow = row0 + r;
        if (grow < N_NODES) {
            *(float4*)(Z + (size_t)grow * D + (lane & 31) * 4) =
                *(const float4*)&Hs[wave][r * HSTR + (lane & 31) * 4];
        }
    }
}

// ---------------------------------------------------------------------------
// BatchNorm statistics (fp32, identical to round 2)
// ---------------------------------------------------------------------------
__global__ void bn_stats(const float* __restrict__ Z, float* __restrict__ stats) {
    __shared__ float red[256];
    int col = threadIdx.x & 127;
    int half = threadIdx.x >> 7;
    float s = 0.f, s2 = 0.f;
    for (int r = blockIdx.x * 2 + half; r < N_NODES; r += gridDim.x * 2) {
        float v = Z[(size_t)r * D + col];
        s += v;
        s2 += v * v;
    }
    red[threadIdx.x] = s;
    __syncthreads();
    if (half == 0) atomicAdd(&stats[col], s + red[threadIdx.x + 128]);
    __syncthreads();
    red[threadIdx.x] = s2;
    __syncthreads();
    if (half == 0) atomicAdd(&stats[D + col], s2 + red[threadIdx.x + 128]);
}

// ---------------------------------------------------------------------------
// Final: zn = BN(Z)*gamma+beta, p = PReLU(zn @ Wp + bp) (fp32, round-2 version)
// ---------------------------------------------------------------------------
__global__ __launch_bounds__(256, 2) void bn_proj(
    const float* __restrict__ Z, const float* __restrict__ stats,
    const float* __restrict__ gamma, const float* __restrict__ beta,
    const float* __restrict__ Wp, const float* __restrict__ bp,
    const float* __restrict__ prelu_a,
    float* __restrict__ zn_out, float* __restrict__ p_out) {
    __shared__ float As[D][TM + 4];
    __shared__ float Ws[D][TN + 4];
    __shared__ float scale_s[D];
    __shared__ float shift_s[D];
    int tid = threadIdx.x;
    int row0 = blockIdx.x * TM;
    int col0 = blockIdx.y * TN;

    if (tid < D) {
        float m = stats[tid] * (1.0f / N_NODES);
        float v = stats[D + tid] * (1.0f / N_NODES) - m * m;
        float rs = rsqrtf(v + BN_EPS);
        float sc = rs * gamma[tid];
        scale_s[tid] = sc;
        shift_s[tid] = beta[tid] - m * sc;
    }
    __syncthreads();

    for (int i = tid; i < D * (TN / 4); i += 256) {
        int k = i >> 4;
        int c = (i & 15) << 2;
        float4 w4 = *(const float4*)(Wp + (size_t)k * D + col0 + c);
        Ws[k][c + 0] = w4.x; Ws[k][c + 1] = w4.y;
        Ws[k][c + 2] = w4.z; Ws[k][c + 3] = w4.w;
    }
    for (int i = tid; i < TM * (D / 4); i += 256) {
        int r = i >> 5;
        int k = (i & 31) << 2;
        int gr = row0 + r;
        float4 v = make_float4(0.f, 0.f, 0.f, 0.f);
        if (gr < N_NODES) {
            v = *(const float4*)(Z + (size_t)gr * D + k);
            v.x = v.x * scale_s[k + 0] + shift_s[k + 0];
            v.y = v.y * scale_s[k + 1] + shift_s[k + 1];
            v.z = v.z * scale_s[k + 2] + shift_s[k + 2];
            v.w = v.w * scale_s[k + 3] + shift_s[k + 3];
            if (blockIdx.y == 0) {
                *(float4*)(zn_out + (size_t)gr * D + k) = v;
            }
        }
        As[k + 0][r] = v.x;
        As[k + 1][r] = v.y;
        As[k + 2][r] = v.z;
        As[k + 3][r] = v.w;
    }
    __syncthreads();

    int colg = tid & 15;
    int rowg = tid >> 4;
    float acc[4][4] = {};
    #pragma unroll 8
    for (int k = 0; k < D; ++k) {
        float4 a4 = *(const float4*)&As[k][rowg * 4];
        float4 w4 = *(const float4*)&Ws[k][colg * 4];
        acc[0][0] += a4.x * w4.x; acc[0][1] += a4.x * w4.y; acc[0][2] += a4.x * w4.z; acc[0][3] += a4.x * w4.w;
        acc[1][0] += a4.y * w4.x; acc[1][1] += a4.y * w4.y; acc[1][2] += a4.y * w4.z; acc[1][3] += a4.y * w4.w;
        acc[2][0] += a4.z * w4.x; acc[2][1] += a4.z * w4.y; acc[2][2] += a4.z * w4.z; acc[2][3] += a4.z * w4.w;
        acc[3][0] += a4.w * w4.x; acc[3][1] += a4.w * w4.y; acc[3][2] += a4.w * w4.z; acc[3][3] += a4.w * w4.w;
    }

    float a = prelu_a[0];
    int cbase = col0 + colg * 4;
    float b0 = bp[cbase + 0], b1 = bp[cbase + 1], b2 = bp[cbase + 2], b3 = bp[cbase + 3];
    #pragma unroll
    for (int r = 0; r < 4; ++r) {
        int gr = row0 + rowg * 4 + r;
        if (gr < N_NODES) {
            float4 o;
            o.x = acc[r][0] + b0;
            o.y = acc[r][1] + b1;
            o.z = acc[r][2] + b2;
            o.w = acc[r][3] + b3;
            o.x = (o.x >= 0.f) ? o.x : a * o.x;
            o.y = (o.y >= 0.f) ? o.y : a * o.y;
            o.z = (o.z >= 0.f) ? o.z : a * o.z;
            o.w = (o.w >= 0.f) ? o.w : a * o.w;
            *(float4*)(p_out + (size_t)gr * D + cbase) = o;
        }
    }
}

// ---------------------------------------------------------------------------
extern "C" void kernel_launch(void* const* d_in, const int* in_sizes, int n_in,
                              void* d_out, int out_size, void* d_ws, size_t ws_size,
                              hipStream_t stream) {
    (void)in_sizes; (void)n_in; (void)out_size; (void)ws_size;
    const float* x     = (const float*)d_in[0];
    const float* ew    = (const float*)d_in[1];
    const float* W1s   = (const float*)d_in[2];
    const float* b1s   = (const float*)d_in[3];
    const float* W2s   = (const float*)d_in[4];
    const float* b2s   = (const float*)d_in[5];
    const float* eps   = (const float*)d_in[6];
    const float* gamma = (const float*)d_in[7];
    const float* beta  = (const float*)d_in[8];
    const float* Wp    = (const float*)d_in[9];
    const float* bp    = (const float*)d_in[10];
    const float* pa    = (const float*)d_in[11];
    const int*   ei    = (const int*)d_in[12];
    const int* srcp = ei;
    const int* dstp = ei + N_EDGES;

    // workspace layout (bytes):
    char* wsb = (char*)d_ws;
    float*  stats  = (float*)wsb;                 wsb += 1024;        // 256 f
    int*    offs   = (int*)wsb;                   wsb += 200016;      // 50004 i
    int*    cursor = (int*)wsb;                   wsb += 200016;      // 50004 i
    int*    ssrc   = (int*)wsb;                   wsb += 3200000;     // 800000 i
    float*  sw     = (float*)wsb;                 wsb += 3200000;     // 800000 f
    ushort* Wpk    = (ushort*)wsb;                wsb += 14 * 16384 * 2; // split weights
    float*  A      = (float*)wsb;                 wsb += (size_t)ND * 4;
    float*  Zb     = (float*)wsb;                 wsb += (size_t)ND * 4;

    float* out_zn = (float*)d_out;
    float* out_p  = out_zn + ND;

    hipMemsetAsync(stats, 0, 256 * sizeof(float), stream);
    hipMemsetAsync(offs, 0, (N_NODES + 1) * sizeof(int), stream);

    pack_w_split<<<(7 * 16384 + 255) / 256, 256, 0, stream>>>(W1s, W2s, Wp, Wpk);

    hist_kernel<<<(N_EDGES + 255) / 256, 256, 0, stream>>>(dstp, offs);
    scan_kernel<<<1, 1024, 0, stream>>>(offs);
    cursor_kernel<<<(N_NODES + 255) / 256, 256, 0, stream>>>(offs, cursor);
    fill_kernel<<<(N_EDGES + 255) / 256, 256, 0, stream>>>(srcp, dstp, ew, cursor, ssrc, sw);

    int mgrid = (N_NODES + 63) / 64;
    dim3 pgrid((N_NODES + TM - 1) / TM, 2);
    const float* zin = x;
    for (int l = 0; l < 3; ++l) {
        gather_agg<<<(N_NODES * 32 + 255) / 256, 256, 0, stream>>>(zin, offs, ssrc, sw, eps, l, A);
        mlp_fused<<<mgrid, 256, 0, stream>>>(A,
            Wpk + (size_t)(2 * l) * 16384,       Wpk + (size_t)(2 * l + 1) * 16384, b1s + (size_t)l * D,
            Wpk + (size_t)(2 * (3 + l)) * 16384, Wpk + (size_t)(2 * (3 + l) + 1) * 16384, b2s + (size_t)l * D,
            Zb);
        zin = Zb;
    }
    bn_stats<<<512, 256, 0, stream>>>(Zb, stats);
    bn_proj<<<pgrid, 256, 0, stream>>>(Zb, stats, gamma, beta, Wp, bp, pa, out_zn, out_p);
}

// Round 5
// 551.790 us; speedup vs baseline: 8.0820x; 1.1210x over previous
//
#include <hip/hip_runtime.h>
#include <hip/hip_fp16.h>

#define N_NODES 50000
#define N_EDGES 800000
#define D 128
#define ND (N_NODES * D)
#define BN_EPS 1e-5f

typedef short bf16x8 __attribute__((ext_vector_type(8)));
typedef float f32x4 __attribute__((ext_vector_type(4)));
typedef unsigned short u16x8 __attribute__((ext_vector_type(8)));

__device__ inline unsigned short f2bf(float f) {
    unsigned int u = __float_as_uint(f);
    u += 0x7FFF + ((u >> 16) & 1);
    return (unsigned short)(u >> 16);
}
__device__ inline float bf2f(unsigned short h) {
    return __uint_as_float(((unsigned int)h) << 16);
}
__device__ inline unsigned short f2h(float f) {
    return __half_as_ushort(__float2half(f));
}
__device__ inline float h2f(unsigned short u) {
    return __half2float(__ushort_as_half(u));
}

// ---------------------------------------------------------------------------
// Convert x (fp32) -> fp16
// ---------------------------------------------------------------------------
__global__ void convert_x(const float* __restrict__ x, ushort* __restrict__ xh) {
    int i = (blockIdx.x * blockDim.x + threadIdx.x) * 4;
    if (i < ND) {
        float4 v = *(const float4*)(x + i);
        *(ushort4*)(xh + i) = make_ushort4(f2h(v.x), f2h(v.y), f2h(v.z), f2h(v.w));
    }
}

// ---------------------------------------------------------------------------
// Pack 7 weight matrices [128x128] fp32 into split-bf16 MFMA B-fragment pairs.
// hi at (2m)*16384 + p, lo at (2m+1)*16384 + p where
// p = c*2048 + kc*512 + lane*8 + j holds W[kc*32+(lane>>4)*8+j][c*16+(lane&15)]
// matrices: 0-2 = W1s, 3-5 = W2s, 6 = Wp
// ---------------------------------------------------------------------------
__global__ void pack_w_split(const float* __restrict__ W1s, const float* __restrict__ W2s,
                             const float* __restrict__ Wp, ushort* __restrict__ out) {
    int idx = blockIdx.x * blockDim.x + threadIdx.x;
    if (idx >= 7 * 16384) return;
    int m = idx >> 14;
    int p = idx & 16383;
    int c = p >> 11;
    int kc = (p >> 9) & 3;
    int lane = (p >> 3) & 63;
    int j = p & 7;
    int k = kc * 32 + (lane >> 4) * 8 + j;
    int col = c * 16 + (lane & 15);
    const float* src = (m < 3) ? (W1s + (size_t)m * 16384)
                     : (m < 6) ? (W2s + (size_t)(m - 3) * 16384)
                               : Wp;
    float v = src[k * 128 + col];
    unsigned short hi = f2bf(v);
    float r = v - bf2f(hi);
    out[(size_t)(2 * m) * 16384 + p] = hi;
    out[(size_t)(2 * m + 1) * 16384 + p] = f2bf(r);
}

// ---------------------------------------------------------------------------
// CSR build
// ---------------------------------------------------------------------------
__global__ void hist_kernel(const int* __restrict__ dst, int* __restrict__ offs) {
    int e = blockIdx.x * blockDim.x + threadIdx.x;
    if (e < N_EDGES) atomicAdd(&offs[dst[e] + 1], 1);
}

__global__ void scan_kernel(int* __restrict__ offs) {
    __shared__ int wsum[16];
    __shared__ int carry_s;
    int tid = threadIdx.x;
    int lane = tid & 63;
    int wave = tid >> 6;
    if (tid == 0) carry_s = 0;
    __syncthreads();
    for (int base = 1; base <= N_NODES; base += 1024) {
        int idx = base + tid;
        int v = (idx <= N_NODES) ? offs[idx] : 0;
        int x = v;
        #pragma unroll
        for (int d = 1; d < 64; d <<= 1) {
            int y = __shfl_up(x, d, 64);
            if (lane >= d) x += y;
        }
        if (lane == 63) wsum[wave] = x;
        __syncthreads();
        if (wave == 0 && lane < 16) {
            int y = wsum[lane];
            #pragma unroll
            for (int d = 1; d < 16; d <<= 1) {
                int t = __shfl_up(y, d, 64);
                if (lane >= d) y += t;
            }
            wsum[lane] = y;
        }
        __syncthreads();
        int waveoff = (wave > 0) ? wsum[wave - 1] : 0;
        int total = wsum[15];
        int out = x + waveoff + carry_s;
        if (idx <= N_NODES) offs[idx] = out;
        __syncthreads();
        if (tid == 0) carry_s += total;
        __syncthreads();
    }
}

__global__ void cursor_kernel(const int* __restrict__ offs, int* __restrict__ cursor) {
    int i = blockIdx.x * blockDim.x + threadIdx.x;
    if (i < N_NODES) cursor[i] = offs[i];
}

__global__ void fill_kernel(const int* __restrict__ src, const int* __restrict__ dst,
                            const float* __restrict__ ew,
                            int* __restrict__ cursor, int* __restrict__ ssrc,
                            float* __restrict__ sw) {
    int e = blockIdx.x * blockDim.x + threadIdx.x;
    if (e < N_EDGES) {
        int d = dst[e];
        int p = atomicAdd(&cursor[d], 1);
        ssrc[p] = src[e];
        sw[p] = ew[e];
    }
}

// ---------------------------------------------------------------------------
// Gather-aggregate + GIN combine (fp16 in, fp32 accumulate, fp32 out):
// out[n] = (1+eps)*z[n] + sum_j w_j * z[src_j]
// 32 lanes per node, each lane owns 4 features (8B reads).
// ---------------------------------------------------------------------------
__global__ void gather_agg_f16(const ushort* __restrict__ z, const int* __restrict__ offs,
                               const int* __restrict__ ssrc, const float* __restrict__ sw,
                               const float* __restrict__ epsp, int layer,
                               float* __restrict__ out) {
    int tid = blockIdx.x * blockDim.x + threadIdx.x;
    int n = tid >> 5;
    if (n >= N_NODES) return;
    int f = (tid & 31) << 2;
    float epsv = 1.0f + epsp[layer];
    int beg = offs[n], end = offs[n + 1];
    ushort4 zi = *(const ushort4*)(z + (size_t)n * D + f);
    float ax = epsv * h2f(zi.x), ay = epsv * h2f(zi.y);
    float az = epsv * h2f(zi.z), aw = epsv * h2f(zi.w);
    for (int j = beg; j < end; ++j) {
        int s = ssrc[j];
        float w = sw[j];
        ushort4 v = *(const ushort4*)(z + (size_t)s * D + f);
        ax += h2f(v.x) * w; ay += h2f(v.y) * w;
        az += h2f(v.z) * w; aw += h2f(v.w) * w;
    }
    *(float4*)(out + (size_t)n * D + f) = make_float4(ax, ay, az, aw);
}

// ---------------------------------------------------------------------------
// Fused GIN MLP, split-bf16 MFMA (fp32 in, fp16 out, ~fp32 accuracy):
// Z = relu(relu(A@W1+b1)@W2+b2)
// 256 threads = 4 waves; each wave computes 16 rows x 128 cols.
// A@W == Ahi@Whi + Alo@Whi + Ahi@Wlo (lo*lo dropped, ~1e-5 rel)
// ---------------------------------------------------------------------------
#define HSTR 132   // floats: 128 + 4 pad
__global__ __launch_bounds__(256) void mlp_fused(
    const float* __restrict__ A,
    const ushort* __restrict__ W1hi, const ushort* __restrict__ W1lo,
    const float* __restrict__ b1,
    const ushort* __restrict__ W2hi, const ushort* __restrict__ W2lo,
    const float* __restrict__ b2, ushort* __restrict__ Z) {
    __shared__ float Hs[4][16 * HSTR];
    int tid = threadIdx.x;
    int lane = tid & 63;
    int wave = tid >> 6;
    int rlo = lane & 15;
    int quad = lane >> 4;
    int row0 = blockIdx.x * 64 + wave * 16;
    int arow = row0 + rlo;
    int ar = (arow < N_NODES) ? arow : (N_NODES - 1);

    const bf16x8* W1h = (const bf16x8*)W1hi;
    const bf16x8* W1l = (const bf16x8*)W1lo;
    const bf16x8* W2h = (const bf16x8*)W2hi;
    const bf16x8* W2l = (const bf16x8*)W2lo;

    // A fragments (split): lane holds A[ar][kc*32 + quad*8 + j]
    bf16x8 ahi[4], alo[4];
    #pragma unroll
    for (int kc = 0; kc < 4; ++kc) {
        const float* p = A + (size_t)ar * D + kc * 32 + quad * 8;
        float4 v0 = *(const float4*)p;
        float4 v1 = *(const float4*)(p + 4);
        float vv[8] = {v0.x, v0.y, v0.z, v0.w, v1.x, v1.y, v1.z, v1.w};
        #pragma unroll
        for (int j = 0; j < 8; ++j) {
            unsigned short h = f2bf(vv[j]);
            ahi[kc][j] = (short)h;
            alo[kc][j] = (short)f2bf(vv[j] - bf2f(h));
        }
    }

    // GEMM1 (3-term split)
    f32x4 acc[8];
    #pragma unroll
    for (int c = 0; c < 8; ++c) acc[c] = (f32x4){0.f, 0.f, 0.f, 0.f};
    #pragma unroll
    for (int c = 0; c < 8; ++c) {
        #pragma unroll
        for (int kc = 0; kc < 4; ++kc) {
            bf16x8 wh = W1h[(c * 4 + kc) * 64 + lane];
            bf16x8 wl = W1l[(c * 4 + kc) * 64 + lane];
            acc[c] = __builtin_amdgcn_mfma_f32_16x16x32_bf16(alo[kc], wh, acc[c], 0, 0, 0);
            acc[c] = __builtin_amdgcn_mfma_f32_16x16x32_bf16(ahi[kc], wl, acc[c], 0, 0, 0);
            acc[c] = __builtin_amdgcn_mfma_f32_16x16x32_bf16(ahi[kc], wh, acc[c], 0, 0, 0);
        }
    }

    // epilogue 1: relu(acc + b1) -> LDS fp32 (C layout: row=quad*4+r, col=c*16+rlo)
    #pragma unroll
    for (int c = 0; c < 8; ++c) {
        int col = c * 16 + rlo;
        float bb = b1[col];
        #pragma unroll
        for (int r = 0; r < 4; ++r) {
            Hs[wave][(quad * 4 + r) * HSTR + col] = fmaxf(acc[c][r] + bb, 0.f);
        }
    }
    __syncthreads();

    // A2 fragments from LDS (split)
    bf16x8 a2hi[4], a2lo[4];
    #pragma unroll
    for (int kc = 0; kc < 4; ++kc) {
        const float* p = &Hs[wave][rlo * HSTR + kc * 32 + quad * 8];
        #pragma unroll
        for (int j = 0; j < 8; ++j) {
            float v = p[j];
            unsigned short h = f2bf(v);
            a2hi[kc][j] = (short)h;
            a2lo[kc][j] = (short)f2bf(v - bf2f(h));
        }
    }

    // GEMM2 (3-term split)
    f32x4 acc2[8];
    #pragma unroll
    for (int c = 0; c < 8; ++c) acc2[c] = (f32x4){0.f, 0.f, 0.f, 0.f};
    #pragma unroll
    for (int c = 0; c < 8; ++c) {
        #pragma unroll
        for (int kc = 0; kc < 4; ++kc) {
            bf16x8 wh = W2h[(c * 4 + kc) * 64 + lane];
            bf16x8 wl = W2l[(c * 4 + kc) * 64 + lane];
            acc2[c] = __builtin_amdgcn_mfma_f32_16x16x32_bf16(a2lo[kc], wh, acc2[c], 0, 0, 0);
            acc2[c] = __builtin_amdgcn_mfma_f32_16x16x32_bf16(a2hi[kc], wl, acc2[c], 0, 0, 0);
            acc2[c] = __builtin_amdgcn_mfma_f32_16x16x32_bf16(a2hi[kc], wh, acc2[c], 0, 0, 0);
        }
    }

    __syncthreads();
    // epilogue 2: relu(acc2 + b2) -> LDS, then coalesced fp16 copy-out
    #pragma unroll
    for (int c = 0; c < 8; ++c) {
        int col = c * 16 + rlo;
        float bb = b2[col];
        #pragma unroll
        for (int r = 0; r < 4; ++r) {
            Hs[wave][(quad * 4 + r) * HSTR + col] = fmaxf(acc2[c][r] + bb, 0.f);
        }
    }
    __syncthreads();
    #pragma unroll
    for (int p2 = 0; p2 < 4; ++p2) {
        int r = p2 * 4 + quad;
        int grow = row0 + r;
        if (grow < N_NODES) {
            float4 lo = *(const float4*)&Hs[wave][r * HSTR + rlo * 8];
            float4 hi = *(const float4*)&Hs[wave][r * HSTR + rlo * 8 + 4];
            ushort us[8] = {f2h(lo.x), f2h(lo.y), f2h(lo.z), f2h(lo.w),
                            f2h(hi.x), f2h(hi.y), f2h(hi.z), f2h(hi.w)};
            *(float4*)(Z + (size_t)grow * D + rlo * 8) = *(const float4*)us;
        }
    }
}

// ---------------------------------------------------------------------------
// BatchNorm statistics from fp16 Z
// ---------------------------------------------------------------------------
__global__ void bn_stats(const ushort* __restrict__ Z, float* __restrict__ stats) {
    __shared__ float red[256];
    int col = threadIdx.x & 127;
    int half = threadIdx.x >> 7;
    float s = 0.f, s2 = 0.f;
    for (int r = blockIdx.x * 2 + half; r < N_NODES; r += gridDim.x * 2) {
        float v = h2f(Z[(size_t)r * D + col]);
        s += v;
        s2 += v * v;
    }
    red[threadIdx.x] = s;
    __syncthreads();
    if (half == 0) atomicAdd(&stats[col], s + red[threadIdx.x + 128]);
    __syncthreads();
    red[threadIdx.x] = s2;
    __syncthreads();
    if (half == 0) atomicAdd(&stats[D + col], s2 + red[threadIdx.x + 128]);
}

// ---------------------------------------------------------------------------
// Final: zn = BN(Z)*gamma+beta (fp32 out), p = PReLU(zn @ Wp + bp) (fp32 out)
// Split-bf16 MFMA GEMM with BN folded into the fragment load.
// ---------------------------------------------------------------------------
#define PSTR 132   // floats
__global__ __launch_bounds__(256) void bn_proj(
    const ushort* __restrict__ Z, const float* __restrict__ stats,
    const float* __restrict__ gamma, const float* __restrict__ beta,
    const ushort* __restrict__ Wphi, const ushort* __restrict__ Wplo,
    const float* __restrict__ bp, const float* __restrict__ prelu_a,
    float* __restrict__ zn_out, float* __restrict__ p_out) {
    __shared__ float sc_s[D];
    __shared__ float sh_s[D];
    __shared__ float Ps[4][16 * PSTR];
    int tid = threadIdx.x;
    int lane = tid & 63;
    int wave = tid >> 6;
    int rlo = lane & 15;
    int quad = lane >> 4;

    if (tid < D) {
        float m = stats[tid] * (1.0f / N_NODES);
        float v = stats[D + tid] * (1.0f / N_NODES) - m * m;
        float rs = rsqrtf(v + BN_EPS);
        float sc = rs * gamma[tid];
        sc_s[tid] = sc;
        sh_s[tid] = beta[tid] - m * sc;
    }
    __syncthreads();

    int row0 = blockIdx.x * 64 + wave * 16;
    int arow = row0 + rlo;
    int ar = (arow < N_NODES) ? arow : (N_NODES - 1);

    const bf16x8* Wh = (const bf16x8*)Wphi;
    const bf16x8* Wl = (const bf16x8*)Wplo;

    // load Z frags, apply BN -> zn (fp32 store + split-bf16 a-frags)
    bf16x8 ahi[4], alo[4];
    #pragma unroll
    for (int kc = 0; kc < 4; ++kc) {
        u16x8 raw = *(const u16x8*)(Z + (size_t)ar * D + kc * 32 + quad * 8);
        float zn[8];
        #pragma unroll
        for (int j = 0; j < 8; ++j) {
            int k = kc * 32 + quad * 8 + j;
            zn[j] = sc_s[k] * h2f(raw[j]) + sh_s[k];
            unsigned short h = f2bf(zn[j]);
            ahi[kc][j] = (short)h;
            alo[kc][j] = (short)f2bf(zn[j] - bf2f(h));
        }
        if (arow < N_NODES) {
            float* dst = zn_out + (size_t)arow * D + kc * 32 + quad * 8;
            *(float4*)dst = make_float4(zn[0], zn[1], zn[2], zn[3]);
            *(float4*)(dst + 4) = make_float4(zn[4], zn[5], zn[6], zn[7]);
        }
    }

    f32x4 acc[8];
    #pragma unroll
    for (int c = 0; c < 8; ++c) acc[c] = (f32x4){0.f, 0.f, 0.f, 0.f};
    #pragma unroll
    for (int c = 0; c < 8; ++c) {
        #pragma unroll
        for (int kc = 0; kc < 4; ++kc) {
            bf16x8 wh = Wh[(c * 4 + kc) * 64 + lane];
            bf16x8 wl = Wl[(c * 4 + kc) * 64 + lane];
            acc[c] = __builtin_amdgcn_mfma_f32_16x16x32_bf16(alo[kc], wh, acc[c], 0, 0, 0);
            acc[c] = __builtin_amdgcn_mfma_f32_16x16x32_bf16(ahi[kc], wl, acc[c], 0, 0, 0);
            acc[c] = __builtin_amdgcn_mfma_f32_16x16x32_bf16(ahi[kc], wh, acc[c], 0, 0, 0);
        }
    }

    float aP = prelu_a[0];
    #pragma unroll
    for (int c = 0; c < 8; ++c) {
        int col = c * 16 + rlo;
        float bb = bp[col];
        #pragma unroll
        for (int r = 0; r < 4; ++r) {
            float v = acc[c][r] + bb;
            v = (v >= 0.f) ? v : aP * v;
            Ps[wave][(quad * 4 + r) * PSTR + col] = v;
        }
    }
    __syncthreads();
    #pragma unroll
    for (int p2 = 0; p2 < 8; ++p2) {
        int r = p2 * 2 + (lane >> 5);
        int grow = row0 + r;
        if (grow < N_NODES) {
            *(float4*)(p_out + (size_t)grow * D + (lane & 31) * 4) =
                *(const float4*)&Ps[wave][r * PSTR + (lane & 31) * 4];
        }
    }
}

// ---------------------------------------------------------------------------
extern "C" void kernel_launch(void* const* d_in, const int* in_sizes, int n_in,
                              void* d_out, int out_size, void* d_ws, size_t ws_size,
                              hipStream_t stream) {
    (void)in_sizes; (void)n_in; (void)out_size; (void)ws_size;
    const float* x     = (const float*)d_in[0];
    const float* ew    = (const float*)d_in[1];
    const float* W1s   = (const float*)d_in[2];
    const float* b1s   = (const float*)d_in[3];
    const float* W2s   = (const float*)d_in[4];
    const float* b2s   = (const float*)d_in[5];
    const float* eps   = (const float*)d_in[6];
    const float* gamma = (const float*)d_in[7];
    const float* beta  = (const float*)d_in[8];
    const float* Wp    = (const float*)d_in[9];
    const float* bp    = (const float*)d_in[10];
    const float* pa    = (const float*)d_in[11];
    const int*   ei    = (const int*)d_in[12];
    const int* srcp = ei;
    const int* dstp = ei + N_EDGES;

    // workspace layout (bytes):
    char* wsb = (char*)d_ws;
    float*  stats  = (float*)wsb;                 wsb += 1024;           // 256 f
    int*    offs   = (int*)wsb;                   wsb += 200016;         // 50004 i
    int*    cursor = (int*)wsb;                   wsb += 200016;         // 50004 i
    int*    ssrc   = (int*)wsb;                   wsb += 3200000;        // 800000 i
    float*  sw     = (float*)wsb;                 wsb += 3200000;        // 800000 f
    ushort* Wpk    = (ushort*)wsb;                wsb += 14 * 16384 * 2; // split weights
    ushort* Xh     = (ushort*)wsb;                wsb += (size_t)ND * 2; // x in fp16
    float*  A      = (float*)wsb;                 wsb += (size_t)ND * 4; // gather out fp32
    ushort* Zh     = (ushort*)wsb;                wsb += (size_t)ND * 2; // layer out fp16

    float* out_zn = (float*)d_out;
    float* out_p  = out_zn + ND;

    hipMemsetAsync(stats, 0, 256 * sizeof(float), stream);
    hipMemsetAsync(offs, 0, (N_NODES + 1) * sizeof(int), stream);

    convert_x<<<(ND / 4 + 255) / 256, 256, 0, stream>>>(x, Xh);
    pack_w_split<<<(7 * 16384 + 255) / 256, 256, 0, stream>>>(W1s, W2s, Wp, Wpk);

    hist_kernel<<<(N_EDGES + 255) / 256, 256, 0, stream>>>(dstp, offs);
    scan_kernel<<<1, 1024, 0, stream>>>(offs);
    cursor_kernel<<<(N_NODES + 255) / 256, 256, 0, stream>>>(offs, cursor);
    fill_kernel<<<(N_EDGES + 255) / 256, 256, 0, stream>>>(srcp, dstp, ew, cursor, ssrc, sw);

    int mgrid = (N_NODES + 63) / 64;
    const ushort* zin = Xh;
    for (int l = 0; l < 3; ++l) {
        gather_agg_f16<<<(N_NODES * 32 + 255) / 256, 256, 0, stream>>>(zin, offs, ssrc, sw, eps, l, A);
        mlp_fused<<<mgrid, 256, 0, stream>>>(A,
            Wpk + (size_t)(2 * l) * 16384,       Wpk + (size_t)(2 * l + 1) * 16384, b1s + (size_t)l * D,
            Wpk + (size_t)(2 * (3 + l)) * 16384, Wpk + (size_t)(2 * (3 + l) + 1) * 16384, b2s + (size_t)l * D,
            Zh);
        zin = Zh;
    }
    bn_stats<<<512, 256, 0, stream>>>(Zh, stats);
    bn_proj<<<mgrid, 256, 0, stream>>>(Zh, stats, gamma, beta,
        Wpk + (size_t)12 * 16384, Wpk + (size_t)13 * 16384, bp, pa, out_zn, out_p);
}

// Round 6
// 497.092 us; speedup vs baseline: 8.9713x; 1.1100x over previous
//
#include <hip/hip_runtime.h>
#include <hip/hip_fp16.h>

#define N_NODES 50000
#define N_EDGES 800000
#define D 128
#define ND (N_NODES * D)
#define BN_EPS 1e-5f

typedef short bf16x8 __attribute__((ext_vector_type(8)));
typedef float f32x4 __attribute__((ext_vector_type(4)));
typedef unsigned short u16x8 __attribute__((ext_vector_type(8)));

__device__ inline unsigned short f2bf(float f) {
    unsigned int u = __float_as_uint(f);
    u += 0x7FFF + ((u >> 16) & 1);
    return (unsigned short)(u >> 16);
}
__device__ inline float bf2f(unsigned short h) {
    return __uint_as_float(((unsigned int)h) << 16);
}
__device__ inline unsigned short f2h(float f) {
    return __half_as_ushort(__float2half(f));
}
__device__ inline float h2f(unsigned short u) {
    return __half2float(__ushort_as_half(u));
}

// ---------------------------------------------------------------------------
// Convert x (fp32) -> fp16
// ---------------------------------------------------------------------------
__global__ void convert_x(const float* __restrict__ x, ushort* __restrict__ xh) {
    int i = (blockIdx.x * blockDim.x + threadIdx.x) * 4;
    if (i < ND) {
        float4 v = *(const float4*)(x + i);
        *(ushort4*)(xh + i) = make_ushort4(f2h(v.x), f2h(v.y), f2h(v.z), f2h(v.w));
    }
}

// ---------------------------------------------------------------------------
// Pack 7 weight matrices [128x128] fp32 into split-bf16 MFMA B-fragment pairs.
// ---------------------------------------------------------------------------
__global__ void pack_w_split(const float* __restrict__ W1s, const float* __restrict__ W2s,
                             const float* __restrict__ Wp, ushort* __restrict__ out) {
    int idx = blockIdx.x * blockDim.x + threadIdx.x;
    if (idx >= 7 * 16384) return;
    int m = idx >> 14;
    int p = idx & 16383;
    int c = p >> 11;
    int kc = (p >> 9) & 3;
    int lane = (p >> 3) & 63;
    int j = p & 7;
    int k = kc * 32 + (lane >> 4) * 8 + j;
    int col = c * 16 + (lane & 15);
    const float* src = (m < 3) ? (W1s + (size_t)m * 16384)
                     : (m < 6) ? (W2s + (size_t)(m - 3) * 16384)
                               : Wp;
    float v = src[k * 128 + col];
    unsigned short hi = f2bf(v);
    float r = v - bf2f(hi);
    out[(size_t)(2 * m) * 16384 + p] = hi;
    out[(size_t)(2 * m + 1) * 16384 + p] = f2bf(r);
}

// ---------------------------------------------------------------------------
// CSR build step 1: histogram of dst into offs[1..N]
// ---------------------------------------------------------------------------
__global__ void hist_kernel(const int* __restrict__ dst, int* __restrict__ offs) {
    int e = blockIdx.x * blockDim.x + threadIdx.x;
    if (e < N_EDGES) atomicAdd(&offs[dst[e] + 1], 1);
}

// ---------------------------------------------------------------------------
// CSR build step 2: in-place inclusive scan over offs[1..N], 8 elts/thread,
// also emits cursor[i] = offs[i] for i in [0, N).
// ---------------------------------------------------------------------------
__global__ void scan_kernel(int* __restrict__ offs, int* __restrict__ cursor) {
    __shared__ int wsum[16];
    __shared__ int carry_s;
    int tid = threadIdx.x;
    int lane = tid & 63;
    int wave = tid >> 6;
    if (tid == 0) { carry_s = 0; cursor[0] = 0; }
    __syncthreads();
    for (int base = 1; base <= N_NODES; base += 8192) {
        int i0 = base + tid * 8;
        int v[8];
        #pragma unroll
        for (int k = 0; k < 8; ++k) {
            int idx = i0 + k;
            v[k] = (idx <= N_NODES) ? offs[idx] : 0;
        }
        #pragma unroll
        for (int k = 1; k < 8; ++k) v[k] += v[k - 1];
        int tsum = v[7];
        int x = tsum;
        #pragma unroll
        for (int d = 1; d < 64; d <<= 1) {
            int y = __shfl_up(x, d, 64);
            if (lane >= d) x += y;
        }
        if (lane == 63) wsum[wave] = x;
        __syncthreads();
        if (wave == 0 && lane < 16) {
            int y = wsum[lane];
            #pragma unroll
            for (int d = 1; d < 16; d <<= 1) {
                int t = __shfl_up(y, d, 64);
                if (lane >= d) y += t;
            }
            wsum[lane] = y;
        }
        __syncthreads();
        int waveoff = (wave > 0) ? wsum[wave - 1] : 0;
        int total = wsum[15];
        int add = (x - tsum) + waveoff + carry_s;
        #pragma unroll
        for (int k = 0; k < 8; ++k) {
            int idx = i0 + k;
            if (idx <= N_NODES) {
                int val = v[k] + add;
                offs[idx] = val;
                if (idx < N_NODES) cursor[idx] = val;
            }
        }
        __syncthreads();
        if (tid == 0) carry_s += total;
        __syncthreads();
    }
}

// ---------------------------------------------------------------------------
// CSR build step 3: bucket-fill interleaved (src, weight) payload by dst.
// Single 8B store per edge (halves dirty-line traffic vs two 4B stores).
// ---------------------------------------------------------------------------
__global__ void fill_kernel(const int* __restrict__ src, const int* __restrict__ dst,
                            const float* __restrict__ ew,
                            int* __restrict__ cursor, uint2* __restrict__ pay) {
    int e = blockIdx.x * blockDim.x + threadIdx.x;
    if (e < N_EDGES) {
        int d = dst[e];
        int p = atomicAdd(&cursor[d], 1);
        pay[p] = make_uint2((unsigned)src[e], __float_as_uint(ew[e]));
    }
}

// ---------------------------------------------------------------------------
// Gather-aggregate + GIN combine (fp16 in, fp32 accumulate, fp32 out):
// out[n] = (1+eps)*z[n] + sum_j w_j * z[src_j]
// 32 lanes per node, each lane owns 4 features (8B reads).
// ---------------------------------------------------------------------------
__global__ void gather_agg_f16(const ushort* __restrict__ z, const int* __restrict__ offs,
                               const uint2* __restrict__ pay,
                               const float* __restrict__ epsp, int layer,
                               float* __restrict__ out) {
    int tid = blockIdx.x * blockDim.x + threadIdx.x;
    int n = tid >> 5;
    if (n >= N_NODES) return;
    int f = (tid & 31) << 2;
    float epsv = 1.0f + epsp[layer];
    int beg = offs[n], end = offs[n + 1];
    ushort4 zi = *(const ushort4*)(z + (size_t)n * D + f);
    float ax = epsv * h2f(zi.x), ay = epsv * h2f(zi.y);
    float az = epsv * h2f(zi.z), aw = epsv * h2f(zi.w);
    for (int j = beg; j < end; ++j) {
        uint2 e = pay[j];
        int s = (int)e.x;
        float w = __uint_as_float(e.y);
        ushort4 v = *(const ushort4*)(z + (size_t)s * D + f);
        ax += h2f(v.x) * w; ay += h2f(v.y) * w;
        az += h2f(v.z) * w; aw += h2f(v.w) * w;
    }
    *(float4*)(out + (size_t)n * D + f) = make_float4(ax, ay, az, aw);
}

// ---------------------------------------------------------------------------
// Fused GIN MLP, split-bf16 MFMA (fp32 in, fp16 out, ~fp32 accuracy):
// Z = relu(relu(A@W1+b1)@W2+b2); if STATS, also accumulate per-column
// sum/sum-of-squares (from the fp32 pre-rounding values) into stats.
// ---------------------------------------------------------------------------
#define HSTR 132   // floats: 128 + 4 pad
template<bool STATS>
__global__ __launch_bounds__(256) void mlp_fused(
    const float* __restrict__ A,
    const ushort* __restrict__ W1hi, const ushort* __restrict__ W1lo,
    const float* __restrict__ b1,
    const ushort* __restrict__ W2hi, const ushort* __restrict__ W2lo,
    const float* __restrict__ b2, ushort* __restrict__ Z,
    float* __restrict__ stats) {
    __shared__ float Hs[4][16 * HSTR];
    __shared__ float red[256];
    int tid = threadIdx.x;
    int lane = tid & 63;
    int wave = tid >> 6;
    int rlo = lane & 15;
    int quad = lane >> 4;
    int blk0 = blockIdx.x * 64;
    int row0 = blk0 + wave * 16;
    int arow = row0 + rlo;
    int ar = (arow < N_NODES) ? arow : (N_NODES - 1);

    const bf16x8* W1h = (const bf16x8*)W1hi;
    const bf16x8* W1l = (const bf16x8*)W1lo;
    const bf16x8* W2h = (const bf16x8*)W2hi;
    const bf16x8* W2l = (const bf16x8*)W2lo;

    // A fragments (split): lane holds A[ar][kc*32 + quad*8 + j]
    bf16x8 ahi[4], alo[4];
    #pragma unroll
    for (int kc = 0; kc < 4; ++kc) {
        const float* p = A + (size_t)ar * D + kc * 32 + quad * 8;
        float4 v0 = *(const float4*)p;
        float4 v1 = *(const float4*)(p + 4);
        float vv[8] = {v0.x, v0.y, v0.z, v0.w, v1.x, v1.y, v1.z, v1.w};
        #pragma unroll
        for (int j = 0; j < 8; ++j) {
            unsigned short h = f2bf(vv[j]);
            ahi[kc][j] = (short)h;
            alo[kc][j] = (short)f2bf(vv[j] - bf2f(h));
        }
    }

    // GEMM1 (3-term split)
    f32x4 acc[8];
    #pragma unroll
    for (int c = 0; c < 8; ++c) acc[c] = (f32x4){0.f, 0.f, 0.f, 0.f};
    #pragma unroll
    for (int c = 0; c < 8; ++c) {
        #pragma unroll
        for (int kc = 0; kc < 4; ++kc) {
            bf16x8 wh = W1h[(c * 4 + kc) * 64 + lane];
            bf16x8 wl = W1l[(c * 4 + kc) * 64 + lane];
            acc[c] = __builtin_amdgcn_mfma_f32_16x16x32_bf16(alo[kc], wh, acc[c], 0, 0, 0);
            acc[c] = __builtin_amdgcn_mfma_f32_16x16x32_bf16(ahi[kc], wl, acc[c], 0, 0, 0);
            acc[c] = __builtin_amdgcn_mfma_f32_16x16x32_bf16(ahi[kc], wh, acc[c], 0, 0, 0);
        }
    }

    // epilogue 1: relu(acc + b1) -> LDS fp32 (C layout: row=quad*4+r, col=c*16+rlo)
    #pragma unroll
    for (int c = 0; c < 8; ++c) {
        int col = c * 16 + rlo;
        float bb = b1[col];
        #pragma unroll
        for (int r = 0; r < 4; ++r) {
            Hs[wave][(quad * 4 + r) * HSTR + col] = fmaxf(acc[c][r] + bb, 0.f);
        }
    }
    __syncthreads();

    // A2 fragments from LDS (split)
    bf16x8 a2hi[4], a2lo[4];
    #pragma unroll
    for (int kc = 0; kc < 4; ++kc) {
        const float* p = &Hs[wave][rlo * HSTR + kc * 32 + quad * 8];
        #pragma unroll
        for (int j = 0; j < 8; ++j) {
            float v = p[j];
            unsigned short h = f2bf(v);
            a2hi[kc][j] = (short)h;
            a2lo[kc][j] = (short)f2bf(v - bf2f(h));
        }
    }

    // GEMM2 (3-term split)
    f32x4 acc2[8];
    #pragma unroll
    for (int c = 0; c < 8; ++c) acc2[c] = (f32x4){0.f, 0.f, 0.f, 0.f};
    #pragma unroll
    for (int c = 0; c < 8; ++c) {
        #pragma unroll
        for (int kc = 0; kc < 4; ++kc) {
            bf16x8 wh = W2h[(c * 4 + kc) * 64 + lane];
            bf16x8 wl = W2l[(c * 4 + kc) * 64 + lane];
            acc2[c] = __builtin_amdgcn_mfma_f32_16x16x32_bf16(a2lo[kc], wh, acc2[c], 0, 0, 0);
            acc2[c] = __builtin_amdgcn_mfma_f32_16x16x32_bf16(a2hi[kc], wl, acc2[c], 0, 0, 0);
            acc2[c] = __builtin_amdgcn_mfma_f32_16x16x32_bf16(a2hi[kc], wh, acc2[c], 0, 0, 0);
        }
    }

    __syncthreads();
    // epilogue 2: relu(acc2 + b2) -> LDS, then coalesced fp16 copy-out
    #pragma unroll
    for (int c = 0; c < 8; ++c) {
        int col = c * 16 + rlo;
        float bb = b2[col];
        #pragma unroll
        for (int r = 0; r < 4; ++r) {
            Hs[wave][(quad * 4 + r) * HSTR + col] = fmaxf(acc2[c][r] + bb, 0.f);
        }
    }
    __syncthreads();
    #pragma unroll
    for (int p2 = 0; p2 < 4; ++p2) {
        int r = p2 * 4 + quad;
        int grow = row0 + r;
        if (grow < N_NODES) {
            float4 lo = *(const float4*)&Hs[wave][r * HSTR + rlo * 8];
            float4 hi = *(const float4*)&Hs[wave][r * HSTR + rlo * 8 + 4];
            ushort us[8] = {f2h(lo.x), f2h(lo.y), f2h(lo.z), f2h(lo.w),
                            f2h(hi.x), f2h(hi.y), f2h(hi.z), f2h(hi.w)};
            *(float4*)(Z + (size_t)grow * D + rlo * 8) = *(const float4*)us;
        }
    }

    if (STATS) {
        // per-block column reduction over the 64 rows in Hs (fp32 values)
        int col = tid & 127;
        int half = tid >> 7;
        float s = 0.f, s2 = 0.f;
        #pragma unroll
        for (int i = 0; i < 32; ++i) {
            int row = half * 32 + i;
            if (blk0 + row < N_NODES) {
                float v = Hs[row >> 4][(row & 15) * HSTR + col];
                s += v;
                s2 += v * v;
            }
        }
        red[tid] = s;
        __syncthreads();
        if (half == 0) atomicAdd(&stats[col], s + red[tid + 128]);
        __syncthreads();
        red[tid] = s2;
        __syncthreads();
        if (half == 0) atomicAdd(&stats[D + col], s2 + red[tid + 128]);
    }
}

// ---------------------------------------------------------------------------
// Final: zn = BN(Z)*gamma+beta (fp32 out), p = PReLU(zn @ Wp + bp) (fp32 out)
// Split-bf16 MFMA GEMM with BN folded into the fragment load.
// ---------------------------------------------------------------------------
#define PSTR 132   // floats
__global__ __launch_bounds__(256) void bn_proj(
    const ushort* __restrict__ Z, const float* __restrict__ stats,
    const float* __restrict__ gamma, const float* __restrict__ beta,
    const ushort* __restrict__ Wphi, const ushort* __restrict__ Wplo,
    const float* __restrict__ bp, const float* __restrict__ prelu_a,
    float* __restrict__ zn_out, float* __restrict__ p_out) {
    __shared__ float sc_s[D];
    __shared__ float sh_s[D];
    __shared__ float Ps[4][16 * PSTR];
    int tid = threadIdx.x;
    int lane = tid & 63;
    int wave = tid >> 6;
    int rlo = lane & 15;
    int quad = lane >> 4;

    if (tid < D) {
        float m = stats[tid] * (1.0f / N_NODES);
        float v = stats[D + tid] * (1.0f / N_NODES) - m * m;
        float rs = rsqrtf(v + BN_EPS);
        float sc = rs * gamma[tid];
        sc_s[tid] = sc;
        sh_s[tid] = beta[tid] - m * sc;
    }
    __syncthreads();

    int row0 = blockIdx.x * 64 + wave * 16;
    int arow = row0 + rlo;
    int ar = (arow < N_NODES) ? arow : (N_NODES - 1);

    const bf16x8* Wh = (const bf16x8*)Wphi;
    const bf16x8* Wl = (const bf16x8*)Wplo;

    // load Z frags, apply BN -> zn (fp32 store + split-bf16 a-frags)
    bf16x8 ahi[4], alo[4];
    #pragma unroll
    for (int kc = 0; kc < 4; ++kc) {
        u16x8 raw = *(const u16x8*)(Z + (size_t)ar * D + kc * 32 + quad * 8);
        float zn[8];
        #pragma unroll
        for (int j = 0; j < 8; ++j) {
            int k = kc * 32 + quad * 8 + j;
            zn[j] = sc_s[k] * h2f(raw[j]) + sh_s[k];
            unsigned short h = f2bf(zn[j]);
            ahi[kc][j] = (short)h;
            alo[kc][j] = (short)f2bf(zn[j] - bf2f(h));
        }
        if (arow < N_NODES) {
            float* dst = zn_out + (size_t)arow * D + kc * 32 + quad * 8;
            *(float4*)dst = make_float4(zn[0], zn[1], zn[2], zn[3]);
            *(float4*)(dst + 4) = make_float4(zn[4], zn[5], zn[6], zn[7]);
        }
    }

    f32x4 acc[8];
    #pragma unroll
    for (int c = 0; c < 8; ++c) acc[c] = (f32x4){0.f, 0.f, 0.f, 0.f};
    #pragma unroll
    for (int c = 0; c < 8; ++c) {
        #pragma unroll
        for (int kc = 0; kc < 4; ++kc) {
            bf16x8 wh = Wh[(c * 4 + kc) * 64 + lane];
            bf16x8 wl = Wl[(c * 4 + kc) * 64 + lane];
            acc[c] = __builtin_amdgcn_mfma_f32_16x16x32_bf16(alo[kc], wh, acc[c], 0, 0, 0);
            acc[c] = __builtin_amdgcn_mfma_f32_16x16x32_bf16(ahi[kc], wl, acc[c], 0, 0, 0);
            acc[c] = __builtin_amdgcn_mfma_f32_16x16x32_bf16(ahi[kc], wh, acc[c], 0, 0, 0);
        }
    }

    float aP = prelu_a[0];
    #pragma unroll
    for (int c = 0; c < 8; ++c) {
        int col = c * 16 + rlo;
        float bb = bp[col];
        #pragma unroll
        for (int r = 0; r < 4; ++r) {
            float v = acc[c][r] + bb;
            v = (v >= 0.f) ? v : aP * v;
            Ps[wave][(quad * 4 + r) * PSTR + col] = v;
        }
    }
    __syncthreads();
    #pragma unroll
    for (int p2 = 0; p2 < 8; ++p2) {
        int r = p2 * 2 + (lane >> 5);
        int grow = row0 + r;
        if (grow < N_NODES) {
            *(float4*)(p_out + (size_t)grow * D + (lane & 31) * 4) =
                *(const float4*)&Ps[wave][r * PSTR + (lane & 31) * 4];
        }
    }
}

// ---------------------------------------------------------------------------
extern "C" void kernel_launch(void* const* d_in, const int* in_sizes, int n_in,
                              void* d_out, int out_size, void* d_ws, size_t ws_size,
                              hipStream_t stream) {
    (void)in_sizes; (void)n_in; (void)out_size; (void)ws_size;
    const float* x     = (const float*)d_in[0];
    const float* ew    = (const float*)d_in[1];
    const float* W1s   = (const float*)d_in[2];
    const float* b1s   = (const float*)d_in[3];
    const float* W2s   = (const float*)d_in[4];
    const float* b2s   = (const float*)d_in[5];
    const float* eps   = (const float*)d_in[6];
    const float* gamma = (const float*)d_in[7];
    const float* beta  = (const float*)d_in[8];
    const float* Wp    = (const float*)d_in[9];
    const float* bp    = (const float*)d_in[10];
    const float* pa    = (const float*)d_in[11];
    const int*   ei    = (const int*)d_in[12];
    const int* srcp = ei;
    const int* dstp = ei + N_EDGES;

    // workspace layout (bytes):
    char* wsb = (char*)d_ws;
    float*  stats  = (float*)wsb;                 wsb += 1024;           // 256 f
    int*    offs   = (int*)wsb;                   wsb += 200016;         // 50004 i
    int*    cursor = (int*)wsb;                   wsb += 200016;         // 50004 i
    uint2*  pay    = (uint2*)wsb;                 wsb += 6400000;        // 800000 uint2
    ushort* Wpk    = (ushort*)wsb;                wsb += 14 * 16384 * 2; // split weights
    ushort* Xh     = (ushort*)wsb;                wsb += (size_t)ND * 2; // x in fp16
    float*  A      = (float*)wsb;                 wsb += (size_t)ND * 4; // gather out fp32
    ushort* Zh     = (ushort*)wsb;                wsb += (size_t)ND * 2; // layer out fp16

    float* out_zn = (float*)d_out;
    float* out_p  = out_zn + ND;

    hipMemsetAsync(stats, 0, 256 * sizeof(float), stream);
    hipMemsetAsync(offs, 0, (N_NODES + 1) * sizeof(int), stream);

    convert_x<<<(ND / 4 + 255) / 256, 256, 0, stream>>>(x, Xh);
    pack_w_split<<<(7 * 16384 + 255) / 256, 256, 0, stream>>>(W1s, W2s, Wp, Wpk);

    hist_kernel<<<(N_EDGES + 255) / 256, 256, 0, stream>>>(dstp, offs);
    scan_kernel<<<1, 1024, 0, stream>>>(offs, cursor);
    fill_kernel<<<(N_EDGES + 255) / 256, 256, 0, stream>>>(srcp, dstp, ew, cursor, pay);

    int mgrid = (N_NODES + 63) / 64;
    const ushort* zin = Xh;
    for (int l = 0; l < 3; ++l) {
        gather_agg_f16<<<(N_NODES * 32 + 255) / 256, 256, 0, stream>>>(zin, offs, pay, eps, l, A);
        if (l < 2) {
            mlp_fused<false><<<mgrid, 256, 0, stream>>>(A,
                Wpk + (size_t)(2 * l) * 16384,       Wpk + (size_t)(2 * l + 1) * 16384, b1s + (size_t)l * D,
                Wpk + (size_t)(2 * (3 + l)) * 16384, Wpk + (size_t)(2 * (3 + l) + 1) * 16384, b2s + (size_t)l * D,
                Zh, stats);
        } else {
            mlp_fused<true><<<mgrid, 256, 0, stream>>>(A,
                Wpk + (size_t)(2 * l) * 16384,       Wpk + (size_t)(2 * l + 1) * 16384, b1s + (size_t)l * D,
                Wpk + (size_t)(2 * (3 + l)) * 16384, Wpk + (size_t)(2 * (3 + l) + 1) * 16384, b2s + (size_t)l * D,
                Zh, stats);
        }
        zin = Zh;
    }
    bn_proj<<<mgrid, 256, 0, stream>>>(Zh, stats, gamma, beta,
        Wpk + (size_t)12 * 16384, Wpk + (size_t)13 * 16384, bp, pa, out_zn, out_p);
}

// Round 7
// 488.117 us; speedup vs baseline: 9.1363x; 1.0184x over previous
//
#include <hip/hip_runtime.h>
#include <hip/hip_fp16.h>

#define N_NODES 50000
#define N_EDGES 800000
#define D 128
#define ND (N_NODES * D)
#define BN_EPS 1e-5f

typedef short bf16x8 __attribute__((ext_vector_type(8)));
typedef float f32x4 __attribute__((ext_vector_type(4)));
typedef unsigned short u16x8 __attribute__((ext_vector_type(8)));

__device__ inline unsigned short f2bf(float f) {
    unsigned int u = __float_as_uint(f);
    u += 0x7FFF + ((u >> 16) & 1);
    return (unsigned short)(u >> 16);
}
__device__ inline float bf2f(unsigned short h) {
    return __uint_as_float(((unsigned int)h) << 16);
}
__device__ inline unsigned short f2h(float f) {
    return __half_as_ushort(__float2half(f));
}
__device__ inline float h2f(unsigned short u) {
    return __half2float(__ushort_as_half(u));
}

// ---------------------------------------------------------------------------
// Convert x (fp32) -> fp16
// ---------------------------------------------------------------------------
__global__ void convert_x(const float* __restrict__ x, ushort* __restrict__ xh) {
    int i = (blockIdx.x * blockDim.x + threadIdx.x) * 4;
    if (i < ND) {
        float4 v = *(const float4*)(x + i);
        *(ushort4*)(xh + i) = make_ushort4(f2h(v.x), f2h(v.y), f2h(v.z), f2h(v.w));
    }
}

// ---------------------------------------------------------------------------
// Pack 7 weight matrices [128x128] fp32 into split-bf16 MFMA B-fragment pairs.
// ---------------------------------------------------------------------------
__global__ void pack_w_split(const float* __restrict__ W1s, const float* __restrict__ W2s,
                             const float* __restrict__ Wp, ushort* __restrict__ out) {
    int idx = blockIdx.x * blockDim.x + threadIdx.x;
    if (idx >= 7 * 16384) return;
    int m = idx >> 14;
    int p = idx & 16383;
    int c = p >> 11;
    int kc = (p >> 9) & 3;
    int lane = (p >> 3) & 63;
    int j = p & 7;
    int k = kc * 32 + (lane >> 4) * 8 + j;
    int col = c * 16 + (lane & 15);
    const float* src = (m < 3) ? (W1s + (size_t)m * 16384)
                     : (m < 6) ? (W2s + (size_t)(m - 3) * 16384)
                               : Wp;
    float v = src[k * 128 + col];
    unsigned short hi = f2bf(v);
    float r = v - bf2f(hi);
    out[(size_t)(2 * m) * 16384 + p] = hi;
    out[(size_t)(2 * m + 1) * 16384 + p] = f2bf(r);
}

// ---------------------------------------------------------------------------
// CSR build step 1: histogram of dst into offs[1..N]
// ---------------------------------------------------------------------------
__global__ void hist_kernel(const int* __restrict__ dst, int* __restrict__ offs) {
    int e = blockIdx.x * blockDim.x + threadIdx.x;
    if (e < N_EDGES) atomicAdd(&offs[dst[e] + 1], 1);
}

// ---------------------------------------------------------------------------
// CSR build step 2: in-place inclusive scan over offs[1..N], 8 elts/thread,
// also emits cursor[i] = offs[i] for i in [0, N).
// ---------------------------------------------------------------------------
__global__ void scan_kernel(int* __restrict__ offs, int* __restrict__ cursor) {
    __shared__ int wsum[16];
    __shared__ int carry_s;
    int tid = threadIdx.x;
    int lane = tid & 63;
    int wave = tid >> 6;
    if (tid == 0) { carry_s = 0; cursor[0] = 0; }
    __syncthreads();
    for (int base = 1; base <= N_NODES; base += 8192) {
        int i0 = base + tid * 8;
        int v[8];
        #pragma unroll
        for (int k = 0; k < 8; ++k) {
            int idx = i0 + k;
            v[k] = (idx <= N_NODES) ? offs[idx] : 0;
        }
        #pragma unroll
        for (int k = 1; k < 8; ++k) v[k] += v[k - 1];
        int tsum = v[7];
        int x = tsum;
        #pragma unroll
        for (int d = 1; d < 64; d <<= 1) {
            int y = __shfl_up(x, d, 64);
            if (lane >= d) x += y;
        }
        if (lane == 63) wsum[wave] = x;
        __syncthreads();
        if (wave == 0 && lane < 16) {
            int y = wsum[lane];
            #pragma unroll
            for (int d = 1; d < 16; d <<= 1) {
                int t = __shfl_up(y, d, 64);
                if (lane >= d) y += t;
            }
            wsum[lane] = y;
        }
        __syncthreads();
        int waveoff = (wave > 0) ? wsum[wave - 1] : 0;
        int total = wsum[15];
        int add = (x - tsum) + waveoff + carry_s;
        #pragma unroll
        for (int k = 0; k < 8; ++k) {
            int idx = i0 + k;
            if (idx <= N_NODES) {
                int val = v[k] + add;
                offs[idx] = val;
                if (idx < N_NODES) cursor[idx] = val;
            }
        }
        __syncthreads();
        if (tid == 0) carry_s += total;
        __syncthreads();
    }
}

// ---------------------------------------------------------------------------
// CSR build step 3: bucket-fill interleaved (src, weight) payload by dst.
// ---------------------------------------------------------------------------
__global__ void fill_kernel(const int* __restrict__ src, const int* __restrict__ dst,
                            const float* __restrict__ ew,
                            int* __restrict__ cursor, uint2* __restrict__ pay) {
    int e = blockIdx.x * blockDim.x + threadIdx.x;
    if (e < N_EDGES) {
        int d = dst[e];
        int p = atomicAdd(&cursor[d], 1);
        pay[p] = make_uint2((unsigned)src[e], __float_as_uint(ew[e]));
    }
}

// ---------------------------------------------------------------------------
// Fused layer: gather-aggregate + GIN combine + 2-layer MLP (split-bf16 MFMA).
// Z = relu(relu(((1+eps)*z + sum_j w_j z[src_j]) @ W1 + b1) @ W2 + b2)
// 256 threads = 4 waves; wave w owns rows blockIdx.x*64 + w*16 .. +15.
// Gather: each 32-lane half-group gathers 8 rows (full 128 features, 4/lane)
// into the wave's LDS tile (fp32), then fragments are read from LDS.
// STATS: also accumulate per-column sum / sum-of-squares into stats.
// ---------------------------------------------------------------------------
#define HSTR 132   // floats: 128 + 4 pad
template<bool STATS>
__global__ __launch_bounds__(256) void layer_fused(
    const ushort* __restrict__ z, const int* __restrict__ offs,
    const uint2* __restrict__ pay, const float* __restrict__ epsp, int layer,
    const ushort* __restrict__ W1hi, const ushort* __restrict__ W1lo,
    const float* __restrict__ b1,
    const ushort* __restrict__ W2hi, const ushort* __restrict__ W2lo,
    const float* __restrict__ b2, ushort* __restrict__ Z,
    float* __restrict__ stats) {
    __shared__ float Hs[4][16 * HSTR];
    __shared__ float red[256];
    int tid = threadIdx.x;
    int lane = tid & 63;
    int wave = tid >> 6;
    int rlo = lane & 15;
    int quad = lane >> 4;
    int blk0 = blockIdx.x * 64;
    int row0 = blk0 + wave * 16;

    // ---- gather phase: 32-lane half-groups, 8 nodes each, 4 features/lane
    {
        int l32 = lane & 31;
        int hgrp = lane >> 5;
        int f = l32 * 4;
        float epsv = 1.0f + epsp[layer];
        #pragma unroll 2
        for (int i = 0; i < 8; ++i) {
            int r = hgrp * 8 + i;
            int n = row0 + r;
            int nn = (n < N_NODES) ? n : (N_NODES - 1);
            int beg = offs[nn], end = offs[nn + 1];
            ushort4 zi = *(const ushort4*)(z + (size_t)nn * D + f);
            float ax = epsv * h2f(zi.x), ay = epsv * h2f(zi.y);
            float az = epsv * h2f(zi.z), aw = epsv * h2f(zi.w);
            int j = beg;
            for (; j + 2 <= end; j += 2) {
                uint2 e0 = pay[j];
                uint2 e1 = pay[j + 1];
                ushort4 v0 = *(const ushort4*)(z + (size_t)e0.x * D + f);
                ushort4 v1 = *(const ushort4*)(z + (size_t)e1.x * D + f);
                float w0 = __uint_as_float(e0.y);
                float w1 = __uint_as_float(e1.y);
                ax += h2f(v0.x) * w0 + h2f(v1.x) * w1;
                ay += h2f(v0.y) * w0 + h2f(v1.y) * w1;
                az += h2f(v0.z) * w0 + h2f(v1.z) * w1;
                aw += h2f(v0.w) * w0 + h2f(v1.w) * w1;
            }
            if (j < end) {
                uint2 e0 = pay[j];
                ushort4 v0 = *(const ushort4*)(z + (size_t)e0.x * D + f);
                float w0 = __uint_as_float(e0.y);
                ax += h2f(v0.x) * w0; ay += h2f(v0.y) * w0;
                az += h2f(v0.z) * w0; aw += h2f(v0.w) * w0;
            }
            *(float4*)&Hs[wave][r * HSTR + f] = make_float4(ax, ay, az, aw);
        }
    }
    __syncthreads();

    const bf16x8* W1h = (const bf16x8*)W1hi;
    const bf16x8* W1l = (const bf16x8*)W1lo;
    const bf16x8* W2h = (const bf16x8*)W2hi;
    const bf16x8* W2l = (const bf16x8*)W2lo;

    // A fragments from LDS (split): lane holds A[row0+rlo][kc*32 + quad*8 + j]
    bf16x8 ahi[4], alo[4];
    #pragma unroll
    for (int kc = 0; kc < 4; ++kc) {
        const float* p = &Hs[wave][rlo * HSTR + kc * 32 + quad * 8];
        #pragma unroll
        for (int j = 0; j < 8; ++j) {
            float v = p[j];
            unsigned short h = f2bf(v);
            ahi[kc][j] = (short)h;
            alo[kc][j] = (short)f2bf(v - bf2f(h));
        }
    }
    __syncthreads();

    // GEMM1 (3-term split)
    f32x4 acc[8];
    #pragma unroll
    for (int c = 0; c < 8; ++c) acc[c] = (f32x4){0.f, 0.f, 0.f, 0.f};
    #pragma unroll
    for (int c = 0; c < 8; ++c) {
        #pragma unroll
        for (int kc = 0; kc < 4; ++kc) {
            bf16x8 wh = W1h[(c * 4 + kc) * 64 + lane];
            bf16x8 wl = W1l[(c * 4 + kc) * 64 + lane];
            acc[c] = __builtin_amdgcn_mfma_f32_16x16x32_bf16(alo[kc], wh, acc[c], 0, 0, 0);
            acc[c] = __builtin_amdgcn_mfma_f32_16x16x32_bf16(ahi[kc], wl, acc[c], 0, 0, 0);
            acc[c] = __builtin_amdgcn_mfma_f32_16x16x32_bf16(ahi[kc], wh, acc[c], 0, 0, 0);
        }
    }

    // epilogue 1: relu(acc + b1) -> LDS fp32 (C layout: row=quad*4+r, col=c*16+rlo)
    #pragma unroll
    for (int c = 0; c < 8; ++c) {
        int col = c * 16 + rlo;
        float bb = b1[col];
        #pragma unroll
        for (int r = 0; r < 4; ++r) {
            Hs[wave][(quad * 4 + r) * HSTR + col] = fmaxf(acc[c][r] + bb, 0.f);
        }
    }
    __syncthreads();

    // A2 fragments from LDS (split)
    bf16x8 a2hi[4], a2lo[4];
    #pragma unroll
    for (int kc = 0; kc < 4; ++kc) {
        const float* p = &Hs[wave][rlo * HSTR + kc * 32 + quad * 8];
        #pragma unroll
        for (int j = 0; j < 8; ++j) {
            float v = p[j];
            unsigned short h = f2bf(v);
            a2hi[kc][j] = (short)h;
            a2lo[kc][j] = (short)f2bf(v - bf2f(h));
        }
    }

    // GEMM2 (3-term split)
    f32x4 acc2[8];
    #pragma unroll
    for (int c = 0; c < 8; ++c) acc2[c] = (f32x4){0.f, 0.f, 0.f, 0.f};
    #pragma unroll
    for (int c = 0; c < 8; ++c) {
        #pragma unroll
        for (int kc = 0; kc < 4; ++kc) {
            bf16x8 wh = W2h[(c * 4 + kc) * 64 + lane];
            bf16x8 wl = W2l[(c * 4 + kc) * 64 + lane];
            acc2[c] = __builtin_amdgcn_mfma_f32_16x16x32_bf16(a2lo[kc], wh, acc2[c], 0, 0, 0);
            acc2[c] = __builtin_amdgcn_mfma_f32_16x16x32_bf16(a2hi[kc], wl, acc2[c], 0, 0, 0);
            acc2[c] = __builtin_amdgcn_mfma_f32_16x16x32_bf16(a2hi[kc], wh, acc2[c], 0, 0, 0);
        }
    }

    __syncthreads();
    // epilogue 2: relu(acc2 + b2) -> LDS, then coalesced fp16 copy-out
    #pragma unroll
    for (int c = 0; c < 8; ++c) {
        int col = c * 16 + rlo;
        float bb = b2[col];
        #pragma unroll
        for (int r = 0; r < 4; ++r) {
            Hs[wave][(quad * 4 + r) * HSTR + col] = fmaxf(acc2[c][r] + bb, 0.f);
        }
    }
    __syncthreads();
    #pragma unroll
    for (int p2 = 0; p2 < 4; ++p2) {
        int r = p2 * 4 + quad;
        int grow = row0 + r;
        if (grow < N_NODES) {
            float4 lo = *(const float4*)&Hs[wave][r * HSTR + rlo * 8];
            float4 hi = *(const float4*)&Hs[wave][r * HSTR + rlo * 8 + 4];
            ushort us[8] = {f2h(lo.x), f2h(lo.y), f2h(lo.z), f2h(lo.w),
                            f2h(hi.x), f2h(hi.y), f2h(hi.z), f2h(hi.w)};
            *(float4*)(Z + (size_t)grow * D + rlo * 8) = *(const float4*)us;
        }
    }

    if (STATS) {
        // per-block column reduction over the 64 rows in Hs (fp32 values)
        int col = tid & 127;
        int half = tid >> 7;
        float s = 0.f, s2 = 0.f;
        #pragma unroll
        for (int i = 0; i < 32; ++i) {
            int row = half * 32 + i;
            if (blk0 + row < N_NODES) {
                float v = Hs[row >> 4][(row & 15) * HSTR + col];
                s += v;
                s2 += v * v;
            }
        }
        red[tid] = s;
        __syncthreads();
        if (half == 0) atomicAdd(&stats[col], s + red[tid + 128]);
        __syncthreads();
        red[tid] = s2;
        __syncthreads();
        if (half == 0) atomicAdd(&stats[D + col], s2 + red[tid + 128]);
    }
}

// ---------------------------------------------------------------------------
// Final: zn = BN(Z)*gamma+beta (fp32 out), p = PReLU(zn @ Wp + bp) (fp32 out)
// Split-bf16 MFMA GEMM with BN folded into the fragment load.
// ---------------------------------------------------------------------------
#define PSTR 132   // floats
__global__ __launch_bounds__(256) void bn_proj(
    const ushort* __restrict__ Z, const float* __restrict__ stats,
    const float* __restrict__ gamma, const float* __restrict__ beta,
    const ushort* __restrict__ Wphi, const ushort* __restrict__ Wplo,
    const float* __restrict__ bp, const float* __restrict__ prelu_a,
    float* __restrict__ zn_out, float* __restrict__ p_out) {
    __shared__ float sc_s[D];
    __shared__ float sh_s[D];
    __shared__ float Ps[4][16 * PSTR];
    int tid = threadIdx.x;
    int lane = tid & 63;
    int wave = tid >> 6;
    int rlo = lane & 15;
    int quad = lane >> 4;

    if (tid < D) {
        float m = stats[tid] * (1.0f / N_NODES);
        float v = stats[D + tid] * (1.0f / N_NODES) - m * m;
        float rs = rsqrtf(v + BN_EPS);
        float sc = rs * gamma[tid];
        sc_s[tid] = sc;
        sh_s[tid] = beta[tid] - m * sc;
    }
    __syncthreads();

    int row0 = blockIdx.x * 64 + wave * 16;
    int arow = row0 + rlo;
    int ar = (arow < N_NODES) ? arow : (N_NODES - 1);

    const bf16x8* Wh = (const bf16x8*)Wphi;
    const bf16x8* Wl = (const bf16x8*)Wplo;

    // load Z frags, apply BN -> zn (fp32 store + split-bf16 a-frags)
    bf16x8 ahi[4], alo[4];
    #pragma unroll
    for (int kc = 0; kc < 4; ++kc) {
        u16x8 raw = *(const u16x8*)(Z + (size_t)ar * D + kc * 32 + quad * 8);
        float zn[8];
        #pragma unroll
        for (int j = 0; j < 8; ++j) {
            int k = kc * 32 + quad * 8 + j;
            zn[j] = sc_s[k] * h2f(raw[j]) + sh_s[k];
            unsigned short h = f2bf(zn[j]);
            ahi[kc][j] = (short)h;
            alo[kc][j] = (short)f2bf(zn[j] - bf2f(h));
        }
        if (arow < N_NODES) {
            float* dst = zn_out + (size_t)arow * D + kc * 32 + quad * 8;
            *(float4*)dst = make_float4(zn[0], zn[1], zn[2], zn[3]);
            *(float4*)(dst + 4) = make_float4(zn[4], zn[5], zn[6], zn[7]);
        }
    }

    f32x4 acc[8];
    #pragma unroll
    for (int c = 0; c < 8; ++c) acc[c] = (f32x4){0.f, 0.f, 0.f, 0.f};
    #pragma unroll
    for (int c = 0; c < 8; ++c) {
        #pragma unroll
        for (int kc = 0; kc < 4; ++kc) {
            bf16x8 wh = Wh[(c * 4 + kc) * 64 + lane];
            bf16x8 wl = Wl[(c * 4 + kc) * 64 + lane];
            acc[c] = __builtin_amdgcn_mfma_f32_16x16x32_bf16(alo[kc], wh, acc[c], 0, 0, 0);
            acc[c] = __builtin_amdgcn_mfma_f32_16x16x32_bf16(ahi[kc], wl, acc[c], 0, 0, 0);
            acc[c] = __builtin_amdgcn_mfma_f32_16x16x32_bf16(ahi[kc], wh, acc[c], 0, 0, 0);
        }
    }

    float aP = prelu_a[0];
    #pragma unroll
    for (int c = 0; c < 8; ++c) {
        int col = c * 16 + rlo;
        float bb = bp[col];
        #pragma unroll
        for (int r = 0; r < 4; ++r) {
            float v = acc[c][r] + bb;
            v = (v >= 0.f) ? v : aP * v;
            Ps[wave][(quad * 4 + r) * PSTR + col] = v;
        }
    }
    __syncthreads();
    #pragma unroll
    for (int p2 = 0; p2 < 8; ++p2) {
        int r = p2 * 2 + (lane >> 5);
        int grow = row0 + r;
        if (grow < N_NODES) {
            *(float4*)(p_out + (size_t)grow * D + (lane & 31) * 4) =
                *(const float4*)&Ps[wave][r * PSTR + (lane & 31) * 4];
        }
    }
}

// ---------------------------------------------------------------------------
extern "C" void kernel_launch(void* const* d_in, const int* in_sizes, int n_in,
                              void* d_out, int out_size, void* d_ws, size_t ws_size,
                              hipStream_t stream) {
    (void)in_sizes; (void)n_in; (void)out_size; (void)ws_size;
    const float* x     = (const float*)d_in[0];
    const float* ew    = (const float*)d_in[1];
    const float* W1s   = (const float*)d_in[2];
    const float* b1s   = (const float*)d_in[3];
    const float* W2s   = (const float*)d_in[4];
    const float* b2s   = (const float*)d_in[5];
    const float* eps   = (const float*)d_in[6];
    const float* gamma = (const float*)d_in[7];
    const float* beta  = (const float*)d_in[8];
    const float* Wp    = (const float*)d_in[9];
    const float* bp    = (const float*)d_in[10];
    const float* pa    = (const float*)d_in[11];
    const int*   ei    = (const int*)d_in[12];
    const int* srcp = ei;
    const int* dstp = ei + N_EDGES;

    // workspace layout (bytes):
    char* wsb = (char*)d_ws;
    float*  stats  = (float*)wsb;                 wsb += 1024;           // 256 f
    int*    offs   = (int*)wsb;                   wsb += 200016;         // 50004 i
    int*    cursor = (int*)wsb;                   wsb += 200016;         // 50004 i
    uint2*  pay    = (uint2*)wsb;                 wsb += 6400000;        // 800000 uint2
    ushort* Wpk    = (ushort*)wsb;                wsb += 14 * 16384 * 2; // split weights
    ushort* Xh     = (ushort*)wsb;                wsb += (size_t)ND * 2; // x in fp16
    ushort* Zh     = (ushort*)wsb;                wsb += (size_t)ND * 2; // layer out fp16

    float* out_zn = (float*)d_out;
    float* out_p  = out_zn + ND;

    hipMemsetAsync(stats, 0, 256 * sizeof(float), stream);
    hipMemsetAsync(offs, 0, (N_NODES + 1) * sizeof(int), stream);

    convert_x<<<(ND / 4 + 255) / 256, 256, 0, stream>>>(x, Xh);
    pack_w_split<<<(7 * 16384 + 255) / 256, 256, 0, stream>>>(W1s, W2s, Wp, Wpk);

    hist_kernel<<<(N_EDGES + 255) / 256, 256, 0, stream>>>(dstp, offs);
    scan_kernel<<<1, 1024, 0, stream>>>(offs, cursor);
    fill_kernel<<<(N_EDGES + 255) / 256, 256, 0, stream>>>(srcp, dstp, ew, cursor, pay);

    int mgrid = (N_NODES + 63) / 64;
    const ushort* zin = Xh;
    for (int l = 0; l < 3; ++l) {
        if (l < 2) {
            layer_fused<false><<<mgrid, 256, 0, stream>>>(zin, offs, pay, eps, l,
                Wpk + (size_t)(2 * l) * 16384,       Wpk + (size_t)(2 * l + 1) * 16384, b1s + (size_t)l * D,
                Wpk + (size_t)(2 * (3 + l)) * 16384, Wpk + (size_t)(2 * (3 + l) + 1) * 16384, b2s + (size_t)l * D,
                Zh, stats);
        } else {
            layer_fused<true><<<mgrid, 256, 0, stream>>>(zin, offs, pay, eps, l,
                Wpk + (size_t)(2 * l) * 16384,       Wpk + (size_t)(2 * l + 1) * 16384, b1s + (size_t)l * D,
                Wpk + (size_t)(2 * (3 + l)) * 16384, Wpk + (size_t)(2 * (3 + l) + 1) * 16384, b2s + (size_t)l * D,
                Zh, stats);
        }
        zin = Zh;
    }
    bn_proj<<<mgrid, 256, 0, stream>>>(Zh, stats, gamma, beta,
        Wpk + (size_t)12 * 16384, Wpk + (size_t)13 * 16384, bp, pa, out_zn, out_p);
}

// Round 9
// 477.106 us; speedup vs baseline: 9.3472x; 1.0231x over previous
//
#include <hip/hip_runtime.h>
#include <hip/hip_fp16.h>

#define N_NODES 50000
#define N_EDGES 800000
#define D 128
#define ND (N_NODES * D)
#define BN_EPS 1e-5f

typedef short bf16x8 __attribute__((ext_vector_type(8)));
typedef float f32x4 __attribute__((ext_vector_type(4)));
typedef unsigned short u16x8 __attribute__((ext_vector_type(8)));

__device__ inline unsigned short f2bf(float f) {
    unsigned int u = __float_as_uint(f);
    u += 0x7FFF + ((u >> 16) & 1);
    return (unsigned short)(u >> 16);
}
__device__ inline float bf2f(unsigned short h) {
    return __uint_as_float(((unsigned int)h) << 16);
}
__device__ inline unsigned short f2h(float f) {
    return __half_as_ushort(__float2half(f));
}
__device__ inline float h2f(unsigned short u) {
    return __half2float(__ushort_as_half(u));
}

// ---------------------------------------------------------------------------
// Convert x (fp32) -> fp16
// ---------------------------------------------------------------------------
__global__ void convert_x(const float* __restrict__ x, ushort* __restrict__ xh) {
    int i = (blockIdx.x * blockDim.x + threadIdx.x) * 4;
    if (i < ND) {
        float4 v = *(const float4*)(x + i);
        *(ushort4*)(xh + i) = make_ushort4(f2h(v.x), f2h(v.y), f2h(v.z), f2h(v.w));
    }
}

// ---------------------------------------------------------------------------
// Pack 7 weight matrices [128x128] fp32 into split-bf16 MFMA B-fragment pairs.
// ---------------------------------------------------------------------------
__global__ void pack_w_split(const float* __restrict__ W1s, const float* __restrict__ W2s,
                             const float* __restrict__ Wp, ushort* __restrict__ out) {
    int idx = blockIdx.x * blockDim.x + threadIdx.x;
    if (idx >= 7 * 16384) return;
    int m = idx >> 14;
    int p = idx & 16383;
    int c = p >> 11;
    int kc = (p >> 9) & 3;
    int lane = (p >> 3) & 63;
    int j = p & 7;
    int k = kc * 32 + (lane >> 4) * 8 + j;
    int col = c * 16 + (lane & 15);
    const float* src = (m < 3) ? (W1s + (size_t)m * 16384)
                     : (m < 6) ? (W2s + (size_t)(m - 3) * 16384)
                               : Wp;
    float v = src[k * 128 + col];
    unsigned short hi = f2bf(v);
    float r = v - bf2f(hi);
    out[(size_t)(2 * m) * 16384 + p] = hi;
    out[(size_t)(2 * m + 1) * 16384 + p] = f2bf(r);
}

// ---------------------------------------------------------------------------
// CSR build step 1: histogram of dst into offs[1..N]
// ---------------------------------------------------------------------------
__global__ void hist_kernel(const int* __restrict__ dst, int* __restrict__ offs) {
    int e = blockIdx.x * blockDim.x + threadIdx.x;
    if (e < N_EDGES) atomicAdd(&offs[dst[e] + 1], 1);
}

// ---------------------------------------------------------------------------
// CSR build step 2: in-place inclusive scan over offs[1..N], 8 elts/thread,
// also emits cursor[i] = offs[i] for i in [0, N).
// ---------------------------------------------------------------------------
__global__ void scan_kernel(int* __restrict__ offs, int* __restrict__ cursor) {
    __shared__ int wsum[16];
    __shared__ int carry_s;
    int tid = threadIdx.x;
    int lane = tid & 63;
    int wave = tid >> 6;
    if (tid == 0) { carry_s = 0; cursor[0] = 0; }
    __syncthreads();
    for (int base = 1; base <= N_NODES; base += 8192) {
        int i0 = base + tid * 8;
        int v[8];
        #pragma unroll
        for (int k = 0; k < 8; ++k) {
            int idx = i0 + k;
            v[k] = (idx <= N_NODES) ? offs[idx] : 0;
        }
        #pragma unroll
        for (int k = 1; k < 8; ++k) v[k] += v[k - 1];
        int tsum = v[7];
        int x = tsum;
        #pragma unroll
        for (int d = 1; d < 64; d <<= 1) {
            int y = __shfl_up(x, d, 64);
            if (lane >= d) x += y;
        }
        if (lane == 63) wsum[wave] = x;
        __syncthreads();
        if (wave == 0 && lane < 16) {
            int y = wsum[lane];
            #pragma unroll
            for (int d = 1; d < 16; d <<= 1) {
                int t = __shfl_up(y, d, 64);
                if (lane >= d) y += t;
            }
            wsum[lane] = y;
        }
        __syncthreads();
        int waveoff = (wave > 0) ? wsum[wave - 1] : 0;
        int total = wsum[15];
        int add = (x - tsum) + waveoff + carry_s;
        #pragma unroll
        for (int k = 0; k < 8; ++k) {
            int idx = i0 + k;
            if (idx <= N_NODES) {
                int val = v[k] + add;
                offs[idx] = val;
                if (idx < N_NODES) cursor[idx] = val;
            }
        }
        __syncthreads();
        if (tid == 0) carry_s += total;
        __syncthreads();
    }
}

// ---------------------------------------------------------------------------
// CSR build step 3: bucket-fill interleaved (src, weight) payload by dst.
// ---------------------------------------------------------------------------
__global__ void fill_kernel(const int* __restrict__ src, const int* __restrict__ dst,
                            const float* __restrict__ ew,
                            int* __restrict__ cursor, uint2* __restrict__ pay) {
    int e = blockIdx.x * blockDim.x + threadIdx.x;
    if (e < N_EDGES) {
        int d = dst[e];
        int p = atomicAdd(&cursor[d], 1);
        pay[p] = make_uint2((unsigned)src[e], __float_as_uint(ew[e]));
    }
}

// ---------------------------------------------------------------------------
// Fused layer (thin blocks): gather + GIN combine + 2-layer MLP (split-bf16
// MFMA).  16 rows per block, 3125 blocks -> 12500 waves (gather needs TLP).
// NOTE: zin and Z MUST be distinct buffers (ping-pong) — in-place update
// races across blocks (round-8 failure: dispatch-timing-dependent reads).
// Gather: 8 half-groups of 32 lanes, 2 rows each, 4 features/lane -> LDS fp32.
// MFMA: 4 waves split the 128 output cols (2 chunks of 16 each); A fragments
// (full K) are read from the shared LDS tile.
// STATS: also accumulate per-column sum / sum-of-squares into stats.
// ---------------------------------------------------------------------------
#define HSTR 132   // floats: 128 + 4 pad
#define ROWS 16
template<bool STATS>
__global__ __launch_bounds__(256) void layer_fused(
    const ushort* __restrict__ z, const int* __restrict__ offs,
    const uint2* __restrict__ pay, const float* __restrict__ epsp, int layer,
    const ushort* __restrict__ W1hi, const ushort* __restrict__ W1lo,
    const float* __restrict__ b1,
    const ushort* __restrict__ W2hi, const ushort* __restrict__ W2lo,
    const float* __restrict__ b2, ushort* __restrict__ Z,
    float* __restrict__ stats) {
    __shared__ float Hs[ROWS * HSTR];
    __shared__ float red[256];
    int tid = threadIdx.x;
    int lane = tid & 63;
    int wave = tid >> 6;
    int rlo = lane & 15;
    int quad = lane >> 4;
    int blk0 = blockIdx.x * ROWS;   // N_NODES = 3125*16 exactly

    // ---- gather phase: 8 half-groups of 32 lanes, 2 rows each
    {
        int l32 = tid & 31;
        int g = tid >> 5;          // 0..7
        int f = l32 * 4;
        float epsv = 1.0f + epsp[layer];
        #pragma unroll
        for (int i = 0; i < 2; ++i) {
            int r = g * 2 + i;
            int n = blk0 + r;
            int beg = offs[n], end = offs[n + 1];
            ushort4 zi = *(const ushort4*)(z + (size_t)n * D + f);
            float ax = epsv * h2f(zi.x), ay = epsv * h2f(zi.y);
            float az = epsv * h2f(zi.z), aw = epsv * h2f(zi.w);
            int j = beg;
            for (; j + 2 <= end; j += 2) {
                uint2 e0 = pay[j];
                uint2 e1 = pay[j + 1];
                ushort4 v0 = *(const ushort4*)(z + (size_t)e0.x * D + f);
                ushort4 v1 = *(const ushort4*)(z + (size_t)e1.x * D + f);
                float w0 = __uint_as_float(e0.y);
                float w1 = __uint_as_float(e1.y);
                ax += h2f(v0.x) * w0 + h2f(v1.x) * w1;
                ay += h2f(v0.y) * w0 + h2f(v1.y) * w1;
                az += h2f(v0.z) * w0 + h2f(v1.z) * w1;
                aw += h2f(v0.w) * w0 + h2f(v1.w) * w1;
            }
            if (j < end) {
                uint2 e0 = pay[j];
                ushort4 v0 = *(const ushort4*)(z + (size_t)e0.x * D + f);
                float w0 = __uint_as_float(e0.y);
                ax += h2f(v0.x) * w0; ay += h2f(v0.y) * w0;
                az += h2f(v0.z) * w0; aw += h2f(v0.w) * w0;
            }
            *(float4*)&Hs[r * HSTR + f] = make_float4(ax, ay, az, aw);
        }
    }
    __syncthreads();

    const bf16x8* W1h = (const bf16x8*)W1hi;
    const bf16x8* W1l = (const bf16x8*)W1lo;
    const bf16x8* W2h = (const bf16x8*)W2hi;
    const bf16x8* W2l = (const bf16x8*)W2lo;

    // A fragments from LDS (split, full K): lane holds A[rlo][kc*32 + quad*8 + j]
    bf16x8 ahi[4], alo[4];
    #pragma unroll
    for (int kc = 0; kc < 4; ++kc) {
        const float* p = &Hs[rlo * HSTR + kc * 32 + quad * 8];
        #pragma unroll
        for (int j = 0; j < 8; ++j) {
            float v = p[j];
            unsigned short h = f2bf(v);
            ahi[kc][j] = (short)h;
            alo[kc][j] = (short)f2bf(v - bf2f(h));
        }
    }
    __syncthreads();

    // GEMM1 (3-term split): wave owns col-chunks {2*wave, 2*wave+1}
    f32x4 acc[2];
    #pragma unroll
    for (int ci = 0; ci < 2; ++ci) acc[ci] = (f32x4){0.f, 0.f, 0.f, 0.f};
    #pragma unroll
    for (int ci = 0; ci < 2; ++ci) {
        int c = wave * 2 + ci;
        #pragma unroll
        for (int kc = 0; kc < 4; ++kc) {
            bf16x8 wh = W1h[(c * 4 + kc) * 64 + lane];
            bf16x8 wl = W1l[(c * 4 + kc) * 64 + lane];
            acc[ci] = __builtin_amdgcn_mfma_f32_16x16x32_bf16(alo[kc], wh, acc[ci], 0, 0, 0);
            acc[ci] = __builtin_amdgcn_mfma_f32_16x16x32_bf16(ahi[kc], wl, acc[ci], 0, 0, 0);
            acc[ci] = __builtin_amdgcn_mfma_f32_16x16x32_bf16(ahi[kc], wh, acc[ci], 0, 0, 0);
        }
    }

    // epilogue 1: relu(acc + b1) -> LDS (C layout: row=quad*4+r, col=c*16+rlo)
    #pragma unroll
    for (int ci = 0; ci < 2; ++ci) {
        int col = (wave * 2 + ci) * 16 + rlo;
        float bb = b1[col];
        #pragma unroll
        for (int r = 0; r < 4; ++r) {
            Hs[(quad * 4 + r) * HSTR + col] = fmaxf(acc[ci][r] + bb, 0.f);
        }
    }
    __syncthreads();

    // A2 fragments from LDS (split, full K)
    bf16x8 a2hi[4], a2lo[4];
    #pragma unroll
    for (int kc = 0; kc < 4; ++kc) {
        const float* p = &Hs[rlo * HSTR + kc * 32 + quad * 8];
        #pragma unroll
        for (int j = 0; j < 8; ++j) {
            float v = p[j];
            unsigned short h = f2bf(v);
            a2hi[kc][j] = (short)h;
            a2lo[kc][j] = (short)f2bf(v - bf2f(h));
        }
    }

    // GEMM2 (3-term split)
    f32x4 acc2[2];
    #pragma unroll
    for (int ci = 0; ci < 2; ++ci) acc2[ci] = (f32x4){0.f, 0.f, 0.f, 0.f};
    #pragma unroll
    for (int ci = 0; ci < 2; ++ci) {
        int c = wave * 2 + ci;
        #pragma unroll
        for (int kc = 0; kc < 4; ++kc) {
            bf16x8 wh = W2h[(c * 4 + kc) * 64 + lane];
            bf16x8 wl = W2l[(c * 4 + kc) * 64 + lane];
            acc2[ci] = __builtin_amdgcn_mfma_f32_16x16x32_bf16(a2lo[kc], wh, acc2[ci], 0, 0, 0);
            acc2[ci] = __builtin_amdgcn_mfma_f32_16x16x32_bf16(a2hi[kc], wl, acc2[ci], 0, 0, 0);
            acc2[ci] = __builtin_amdgcn_mfma_f32_16x16x32_bf16(a2hi[kc], wh, acc2[ci], 0, 0, 0);
        }
    }

    __syncthreads();
    // epilogue 2: relu(acc2 + b2) -> LDS
    #pragma unroll
    for (int ci = 0; ci < 2; ++ci) {
        int col = (wave * 2 + ci) * 16 + rlo;
        float bb = b2[col];
        #pragma unroll
        for (int r = 0; r < 4; ++r) {
            Hs[(quad * 4 + r) * HSTR + col] = fmaxf(acc2[ci][r] + bb, 0.f);
        }
    }
    __syncthreads();

    // coalesced fp16 copy-out: 16 rows x 16 col-groups of 8
    {
        int row = tid >> 4;
        int cg = tid & 15;
        int grow = blk0 + row;
        float4 lo = *(const float4*)&Hs[row * HSTR + cg * 8];
        float4 hi = *(const float4*)&Hs[row * HSTR + cg * 8 + 4];
        ushort us[8] = {f2h(lo.x), f2h(lo.y), f2h(lo.z), f2h(lo.w),
                        f2h(hi.x), f2h(hi.y), f2h(hi.z), f2h(hi.w)};
        *(float4*)(Z + (size_t)grow * D + cg * 8) = *(const float4*)us;
    }

    if (STATS) {
        // per-block column reduction over the 16 rows in Hs (fp32 values)
        int col = tid & 127;
        int half = tid >> 7;
        float s = 0.f, s2 = 0.f;
        #pragma unroll
        for (int i = 0; i < 8; ++i) {
            int row = half * 8 + i;
            float v = Hs[row * HSTR + col];
            s += v;
            s2 += v * v;
        }
        red[tid] = s;
        __syncthreads();
        if (half == 0) atomicAdd(&stats[col], s + red[tid + 128]);
        __syncthreads();
        red[tid] = s2;
        __syncthreads();
        if (half == 0) atomicAdd(&stats[D + col], s2 + red[tid + 128]);
    }
}

// ---------------------------------------------------------------------------
// Final: zn = BN(Z)*gamma+beta (fp32 out), p = PReLU(zn @ Wp + bp) (fp32 out)
// Split-bf16 MFMA GEMM with BN folded into the fragment load.
// ---------------------------------------------------------------------------
#define PSTR 132   // floats
__global__ __launch_bounds__(256) void bn_proj(
    const ushort* __restrict__ Z, const float* __restrict__ stats,
    const float* __restrict__ gamma, const float* __restrict__ beta,
    const ushort* __restrict__ Wphi, const ushort* __restrict__ Wplo,
    const float* __restrict__ bp, const float* __restrict__ prelu_a,
    float* __restrict__ zn_out, float* __restrict__ p_out) {
    __shared__ float sc_s[D];
    __shared__ float sh_s[D];
    __shared__ float Ps[4][16 * PSTR];
    int tid = threadIdx.x;
    int lane = tid & 63;
    int wave = tid >> 6;
    int rlo = lane & 15;
    int quad = lane >> 4;

    if (tid < D) {
        float m = stats[tid] * (1.0f / N_NODES);
        float v = stats[D + tid] * (1.0f / N_NODES) - m * m;
        float rs = rsqrtf(v + BN_EPS);
        float sc = rs * gamma[tid];
        sc_s[tid] = sc;
        sh_s[tid] = beta[tid] - m * sc;
    }
    __syncthreads();

    int row0 = blockIdx.x * 64 + wave * 16;
    int arow = row0 + rlo;
    int ar = (arow < N_NODES) ? arow : (N_NODES - 1);

    const bf16x8* Wh = (const bf16x8*)Wphi;
    const bf16x8* Wl = (const bf16x8*)Wplo;

    // load Z frags, apply BN -> zn (fp32 store + split-bf16 a-frags)
    bf16x8 ahi[4], alo[4];
    #pragma unroll
    for (int kc = 0; kc < 4; ++kc) {
        u16x8 raw = *(const u16x8*)(Z + (size_t)ar * D + kc * 32 + quad * 8);
        float zn[8];
        #pragma unroll
        for (int j = 0; j < 8; ++j) {
            int k = kc * 32 + quad * 8 + j;
            zn[j] = sc_s[k] * h2f(raw[j]) + sh_s[k];
            unsigned short h = f2bf(zn[j]);
            ahi[kc][j] = (short)h;
            alo[kc][j] = (short)f2bf(zn[j] - bf2f(h));
        }
        if (arow < N_NODES) {
            float* dst = zn_out + (size_t)arow * D + kc * 32 + quad * 8;
            *(float4*)dst = make_float4(zn[0], zn[1], zn[2], zn[3]);
            *(float4*)(dst + 4) = make_float4(zn[4], zn[5], zn[6], zn[7]);
        }
    }

    f32x4 acc[8];
    #pragma unroll
    for (int c = 0; c < 8; ++c) acc[c] = (f32x4){0.f, 0.f, 0.f, 0.f};
    #pragma unroll
    for (int c = 0; c < 8; ++c) {
        #pragma unroll
        for (int kc = 0; kc < 4; ++kc) {
            bf16x8 wh = Wh[(c * 4 + kc) * 64 + lane];
            bf16x8 wl = Wl[(c * 4 + kc) * 64 + lane];
            acc[c] = __builtin_amdgcn_mfma_f32_16x16x32_bf16(alo[kc], wh, acc[c], 0, 0, 0);
            acc[c] = __builtin_amdgcn_mfma_f32_16x16x32_bf16(ahi[kc], wl, acc[c], 0, 0, 0);
            acc[c] = __builtin_amdgcn_mfma_f32_16x16x32_bf16(ahi[kc], wh, acc[c], 0, 0, 0);
        }
    }

    float aP = prelu_a[0];
    #pragma unroll
    for (int c = 0; c < 8; ++c) {
        int col = c * 16 + rlo;
        float bb = bp[col];
        #pragma unroll
        for (int r = 0; r < 4; ++r) {
            float v = acc[c][r] + bb;
            v = (v >= 0.f) ? v : aP * v;
            Ps[wave][(quad * 4 + r) * PSTR + col] = v;
        }
    }
    __syncthreads();
    #pragma unroll
    for (int p2 = 0; p2 < 8; ++p2) {
        int r = p2 * 2 + (lane >> 5);
        int grow = row0 + r;
        if (grow < N_NODES) {
            *(float4*)(p_out + (size_t)grow * D + (lane & 31) * 4) =
                *(const float4*)&Ps[wave][r * PSTR + (lane & 31) * 4];
        }
    }
}

// ---------------------------------------------------------------------------
extern "C" void kernel_launch(void* const* d_in, const int* in_sizes, int n_in,
                              void* d_out, int out_size, void* d_ws, size_t ws_size,
                              hipStream_t stream) {
    (void)in_sizes; (void)n_in; (void)out_size; (void)ws_size;
    const float* x     = (const float*)d_in[0];
    const float* ew    = (const float*)d_in[1];
    const float* W1s   = (const float*)d_in[2];
    const float* b1s   = (const float*)d_in[3];
    const float* W2s   = (const float*)d_in[4];
    const float* b2s   = (const float*)d_in[5];
    const float* eps   = (const float*)d_in[6];
    const float* gamma = (const float*)d_in[7];
    const float* beta  = (const float*)d_in[8];
    const float* Wp    = (const float*)d_in[9];
    const float* bp    = (const float*)d_in[10];
    const float* pa    = (const float*)d_in[11];
    const int*   ei    = (const int*)d_in[12];
    const int* srcp = ei;
    const int* dstp = ei + N_EDGES;

    // workspace layout (bytes):
    char* wsb = (char*)d_ws;
    float*  stats  = (float*)wsb;                 wsb += 1024;           // 256 f
    int*    offs   = (int*)wsb;                   wsb += 200016;         // 50004 i
    int*    cursor = (int*)wsb;                   wsb += 200016;         // 50004 i
    uint2*  pay    = (uint2*)wsb;                 wsb += 6400000;        // 800000 uint2
    ushort* Wpk    = (ushort*)wsb;                wsb += 14 * 16384 * 2; // split weights
    ushort* Xh     = (ushort*)wsb;                wsb += (size_t)ND * 2; // x in fp16
    ushort* Z0     = (ushort*)wsb;                wsb += (size_t)ND * 2; // ping
    ushort* Z1     = (ushort*)wsb;                wsb += (size_t)ND * 2; // pong

    float* out_zn = (float*)d_out;
    float* out_p  = out_zn + ND;

    hipMemsetAsync(stats, 0, 256 * sizeof(float), stream);
    hipMemsetAsync(offs, 0, (N_NODES + 1) * sizeof(int), stream);

    convert_x<<<(ND / 4 + 255) / 256, 256, 0, stream>>>(x, Xh);
    pack_w_split<<<(7 * 16384 + 255) / 256, 256, 0, stream>>>(W1s, W2s, Wp, Wpk);

    hist_kernel<<<(N_EDGES + 255) / 256, 256, 0, stream>>>(dstp, offs);
    scan_kernel<<<1, 1024, 0, stream>>>(offs, cursor);
    fill_kernel<<<(N_EDGES + 255) / 256, 256, 0, stream>>>(srcp, dstp, ew, cursor, pay);

    int lgrid = N_NODES / ROWS;           // 3125 blocks of 16 rows
    int pgrid = (N_NODES + 63) / 64;      // bn_proj: 64-row blocks

    // ping-pong: Xh -> Z0 -> Z1 -> Z0   (never in-place: cross-block RAW race)
    const ushort* zin = Xh;
    ushort* zout = Z0;
    for (int l = 0; l < 3; ++l) {
        if (l < 2) {
            layer_fused<false><<<lgrid, 256, 0, stream>>>(zin, offs, pay, eps, l,
                Wpk + (size_t)(2 * l) * 16384,       Wpk + (size_t)(2 * l + 1) * 16384, b1s + (size_t)l * D,
                Wpk + (size_t)(2 * (3 + l)) * 16384, Wpk + (size_t)(2 * (3 + l) + 1) * 16384, b2s + (size_t)l * D,
                zout, stats);
        } else {
            layer_fused<true><<<lgrid, 256, 0, stream>>>(zin, offs, pay, eps, l,
                Wpk + (size_t)(2 * l) * 16384,       Wpk + (size_t)(2 * l + 1) * 16384, b1s + (size_t)l * D,
                Wpk + (size_t)(2 * (3 + l)) * 16384, Wpk + (size_t)(2 * (3 + l) + 1) * 16384, b2s + (size_t)l * D,
                zout, stats);
        }
        zin = zout;
        zout = (zout == Z0) ? Z1 : Z0;
    }
    // final layer output is Z0 (Xh -> Z0 -> Z1 -> Z0)
    bn_proj<<<pgrid, 256, 0, stream>>>(Z0, stats, gamma, beta,
        Wpk + (size_t)12 * 16384, Wpk + (size_t)13 * 16384, bp, pa, out_zn, out_p);
}

// Round 10
// 438.813 us; speedup vs baseline: 10.1628x; 1.0873x over previous
//
#include <hip/hip_runtime.h>
#include <hip/hip_fp16.h>

#define N_NODES 50000
#define N_EDGES 800000
#define D 128
#define ND (N_NODES * D)
#define BN_EPS 1e-5f

typedef short bf16x8 __attribute__((ext_vector_type(8)));
typedef float f32x4 __attribute__((ext_vector_type(4)));
typedef unsigned short u16x8 __attribute__((ext_vector_type(8)));

__device__ inline unsigned short f2bf(float f) {
    unsigned int u = __float_as_uint(f);
    u += 0x7FFF + ((u >> 16) & 1);
    return (unsigned short)(u >> 16);
}
__device__ inline float bf2f(unsigned short h) {
    return __uint_as_float(((unsigned int)h) << 16);
}
__device__ inline unsigned short f2h(float f) {
    return __half_as_ushort(__float2half(f));
}
__device__ inline float h2f(unsigned short u) {
    return __half2float(__ushort_as_half(u));
}

// ---------------------------------------------------------------------------
// Convert x (fp32) -> fp16
// ---------------------------------------------------------------------------
__global__ void convert_x(const float* __restrict__ x, ushort* __restrict__ xh) {
    int i = (blockIdx.x * blockDim.x + threadIdx.x) * 4;
    if (i < ND) {
        float4 v = *(const float4*)(x + i);
        *(ushort4*)(xh + i) = make_ushort4(f2h(v.x), f2h(v.y), f2h(v.z), f2h(v.w));
    }
}

// ---------------------------------------------------------------------------
// Pack 7 weight matrices [128x128] fp32 into split-bf16 MFMA B-fragment pairs.
// ---------------------------------------------------------------------------
__global__ void pack_w_split(const float* __restrict__ W1s, const float* __restrict__ W2s,
                             const float* __restrict__ Wp, ushort* __restrict__ out) {
    int idx = blockIdx.x * blockDim.x + threadIdx.x;
    if (idx >= 7 * 16384) return;
    int m = idx >> 14;
    int p = idx & 16383;
    int c = p >> 11;
    int kc = (p >> 9) & 3;
    int lane = (p >> 3) & 63;
    int j = p & 7;
    int k = kc * 32 + (lane >> 4) * 8 + j;
    int col = c * 16 + (lane & 15);
    const float* src = (m < 3) ? (W1s + (size_t)m * 16384)
                     : (m < 6) ? (W2s + (size_t)(m - 3) * 16384)
                               : Wp;
    float v = src[k * 128 + col];
    unsigned short hi = f2bf(v);
    float r = v - bf2f(hi);
    out[(size_t)(2 * m) * 16384 + p] = hi;
    out[(size_t)(2 * m + 1) * 16384 + p] = f2bf(r);
}

// ---------------------------------------------------------------------------
// CSR build step 1: histogram of dst into offs[1..N]
// ---------------------------------------------------------------------------
__global__ void hist_kernel(const int* __restrict__ dst, int* __restrict__ offs) {
    int e = blockIdx.x * blockDim.x + threadIdx.x;
    if (e < N_EDGES) atomicAdd(&offs[dst[e] + 1], 1);
}

// ---------------------------------------------------------------------------
// CSR build step 2: in-place inclusive scan over offs[1..N], 8 elts/thread,
// also emits cursor[i] = offs[i] for i in [0, N).
// ---------------------------------------------------------------------------
__global__ void scan_kernel(int* __restrict__ offs, int* __restrict__ cursor) {
    __shared__ int wsum[16];
    __shared__ int carry_s;
    int tid = threadIdx.x;
    int lane = tid & 63;
    int wave = tid >> 6;
    if (tid == 0) { carry_s = 0; cursor[0] = 0; }
    __syncthreads();
    for (int base = 1; base <= N_NODES; base += 8192) {
        int i0 = base + tid * 8;
        int v[8];
        #pragma unroll
        for (int k = 0; k < 8; ++k) {
            int idx = i0 + k;
            v[k] = (idx <= N_NODES) ? offs[idx] : 0;
        }
        #pragma unroll
        for (int k = 1; k < 8; ++k) v[k] += v[k - 1];
        int tsum = v[7];
        int x = tsum;
        #pragma unroll
        for (int d = 1; d < 64; d <<= 1) {
            int y = __shfl_up(x, d, 64);
            if (lane >= d) x += y;
        }
        if (lane == 63) wsum[wave] = x;
        __syncthreads();
        if (wave == 0 && lane < 16) {
            int y = wsum[lane];
            #pragma unroll
            for (int d = 1; d < 16; d <<= 1) {
                int t = __shfl_up(y, d, 64);
                if (lane >= d) y += t;
            }
            wsum[lane] = y;
        }
        __syncthreads();
        int waveoff = (wave > 0) ? wsum[wave - 1] : 0;
        int total = wsum[15];
        int add = (x - tsum) + waveoff + carry_s;
        #pragma unroll
        for (int k = 0; k < 8; ++k) {
            int idx = i0 + k;
            if (idx <= N_NODES) {
                int val = v[k] + add;
                offs[idx] = val;
                if (idx < N_NODES) cursor[idx] = val;
            }
        }
        __syncthreads();
        if (tid == 0) carry_s += total;
        __syncthreads();
    }
}

// ---------------------------------------------------------------------------
// CSR build step 3: bucket-fill interleaved (src, weight) payload by dst.
// ---------------------------------------------------------------------------
__global__ void fill_kernel(const int* __restrict__ src, const int* __restrict__ dst,
                            const float* __restrict__ ew,
                            int* __restrict__ cursor, uint2* __restrict__ pay) {
    int e = blockIdx.x * blockDim.x + threadIdx.x;
    if (e < N_EDGES) {
        int d = dst[e];
        int p = atomicAdd(&cursor[d], 1);
        pay[p] = make_uint2((unsigned)src[e], __float_as_uint(ew[e]));
    }
}

// ---------------------------------------------------------------------------
// Gather-aggregate + GIN combine (fp16 in, fp32 accumulate, fp16 out):
// A[n] = fp16( (1+eps)*z[n] + sum_j w_j * z[src_j] )
// One node per 32-lane group (max TLP, no barriers), 4 features/lane,
// edge loop unrolled x4 for memory-level parallelism.
// ---------------------------------------------------------------------------
__global__ void gather_agg_f16(const ushort* __restrict__ z, const int* __restrict__ offs,
                               const uint2* __restrict__ pay,
                               const float* __restrict__ epsp, int layer,
                               ushort* __restrict__ A) {
    int tid = blockIdx.x * blockDim.x + threadIdx.x;
    int n = tid >> 5;
    if (n >= N_NODES) return;
    int f = (tid & 31) << 2;
    float epsv = 1.0f + epsp[layer];
    int beg = offs[n], end = offs[n + 1];
    ushort4 zi = *(const ushort4*)(z + (size_t)n * D + f);
    float ax = epsv * h2f(zi.x), ay = epsv * h2f(zi.y);
    float az = epsv * h2f(zi.z), aw = epsv * h2f(zi.w);
    int j = beg;
    for (; j + 4 <= end; j += 4) {
        uint2 e0 = pay[j];
        uint2 e1 = pay[j + 1];
        uint2 e2 = pay[j + 2];
        uint2 e3 = pay[j + 3];
        ushort4 v0 = *(const ushort4*)(z + (size_t)e0.x * D + f);
        ushort4 v1 = *(const ushort4*)(z + (size_t)e1.x * D + f);
        ushort4 v2 = *(const ushort4*)(z + (size_t)e2.x * D + f);
        ushort4 v3 = *(const ushort4*)(z + (size_t)e3.x * D + f);
        float w0 = __uint_as_float(e0.y);
        float w1 = __uint_as_float(e1.y);
        float w2 = __uint_as_float(e2.y);
        float w3 = __uint_as_float(e3.y);
        ax += h2f(v0.x) * w0 + h2f(v1.x) * w1 + h2f(v2.x) * w2 + h2f(v3.x) * w3;
        ay += h2f(v0.y) * w0 + h2f(v1.y) * w1 + h2f(v2.y) * w2 + h2f(v3.y) * w3;
        az += h2f(v0.z) * w0 + h2f(v1.z) * w1 + h2f(v2.z) * w2 + h2f(v3.z) * w3;
        aw += h2f(v0.w) * w0 + h2f(v1.w) * w1 + h2f(v2.w) * w2 + h2f(v3.w) * w3;
    }
    for (; j < end; ++j) {
        uint2 e0 = pay[j];
        ushort4 v0 = *(const ushort4*)(z + (size_t)e0.x * D + f);
        float w0 = __uint_as_float(e0.y);
        ax += h2f(v0.x) * w0; ay += h2f(v0.y) * w0;
        az += h2f(v0.z) * w0; aw += h2f(v0.w) * w0;
    }
    *(ushort4*)(A + (size_t)n * D + f) = make_ushort4(f2h(ax), f2h(ay), f2h(az), f2h(aw));
}

// ---------------------------------------------------------------------------
// Fused GIN MLP, split-bf16 MFMA (fp16 in/out, ~fp32 GEMM accuracy):
// Z = relu(relu(A@W1+b1)@W2+b2); 64 rows/block, 4 waves x 16 rows.
// A fragments straight from global (16B/lane contiguous).
// STATS: accumulate per-column sum / sum-of-squares (fp32 pre-rounding).
// ---------------------------------------------------------------------------
#define HSTR 132   // floats: 128 + 4 pad
template<bool STATS>
__global__ __launch_bounds__(256) void mlp_fused(
    const ushort* __restrict__ A,
    const ushort* __restrict__ W1hi, const ushort* __restrict__ W1lo,
    const float* __restrict__ b1,
    const ushort* __restrict__ W2hi, const ushort* __restrict__ W2lo,
    const float* __restrict__ b2, ushort* __restrict__ Z,
    float* __restrict__ stats) {
    __shared__ float Hs[4][16 * HSTR];
    __shared__ float red[256];
    int tid = threadIdx.x;
    int lane = tid & 63;
    int wave = tid >> 6;
    int rlo = lane & 15;
    int quad = lane >> 4;
    int blk0 = blockIdx.x * 64;
    int row0 = blk0 + wave * 16;
    int arow = row0 + rlo;
    int ar = (arow < N_NODES) ? arow : (N_NODES - 1);

    const bf16x8* W1h = (const bf16x8*)W1hi;
    const bf16x8* W1l = (const bf16x8*)W1lo;
    const bf16x8* W2h = (const bf16x8*)W2hi;
    const bf16x8* W2l = (const bf16x8*)W2lo;

    // A fragments from global fp16 (split): lane holds A[ar][kc*32 + quad*8 + j]
    bf16x8 ahi[4], alo[4];
    #pragma unroll
    for (int kc = 0; kc < 4; ++kc) {
        u16x8 raw = *(const u16x8*)(A + (size_t)ar * D + kc * 32 + quad * 8);
        #pragma unroll
        for (int j = 0; j < 8; ++j) {
            float v = h2f(raw[j]);
            unsigned short h = f2bf(v);
            ahi[kc][j] = (short)h;
            alo[kc][j] = (short)f2bf(v - bf2f(h));
        }
    }

    // GEMM1 (3-term split)
    f32x4 acc[8];
    #pragma unroll
    for (int c = 0; c < 8; ++c) acc[c] = (f32x4){0.f, 0.f, 0.f, 0.f};
    #pragma unroll
    for (int c = 0; c < 8; ++c) {
        #pragma unroll
        for (int kc = 0; kc < 4; ++kc) {
            bf16x8 wh = W1h[(c * 4 + kc) * 64 + lane];
            bf16x8 wl = W1l[(c * 4 + kc) * 64 + lane];
            acc[c] = __builtin_amdgcn_mfma_f32_16x16x32_bf16(alo[kc], wh, acc[c], 0, 0, 0);
            acc[c] = __builtin_amdgcn_mfma_f32_16x16x32_bf16(ahi[kc], wl, acc[c], 0, 0, 0);
            acc[c] = __builtin_amdgcn_mfma_f32_16x16x32_bf16(ahi[kc], wh, acc[c], 0, 0, 0);
        }
    }

    // epilogue 1: relu(acc + b1) -> LDS fp32 (C layout: row=quad*4+r, col=c*16+rlo)
    #pragma unroll
    for (int c = 0; c < 8; ++c) {
        int col = c * 16 + rlo;
        float bb = b1[col];
        #pragma unroll
        for (int r = 0; r < 4; ++r) {
            Hs[wave][(quad * 4 + r) * HSTR + col] = fmaxf(acc[c][r] + bb, 0.f);
        }
    }
    __syncthreads();

    // A2 fragments from LDS (split)
    bf16x8 a2hi[4], a2lo[4];
    #pragma unroll
    for (int kc = 0; kc < 4; ++kc) {
        const float* p = &Hs[wave][rlo * HSTR + kc * 32 + quad * 8];
        #pragma unroll
        for (int j = 0; j < 8; ++j) {
            float v = p[j];
            unsigned short h = f2bf(v);
            a2hi[kc][j] = (short)h;
            a2lo[kc][j] = (short)f2bf(v - bf2f(h));
        }
    }

    // GEMM2 (3-term split)
    f32x4 acc2[8];
    #pragma unroll
    for (int c = 0; c < 8; ++c) acc2[c] = (f32x4){0.f, 0.f, 0.f, 0.f};
    #pragma unroll
    for (int c = 0; c < 8; ++c) {
        #pragma unroll
        for (int kc = 0; kc < 4; ++kc) {
            bf16x8 wh = W2h[(c * 4 + kc) * 64 + lane];
            bf16x8 wl = W2l[(c * 4 + kc) * 64 + lane];
            acc2[c] = __builtin_amdgcn_mfma_f32_16x16x32_bf16(a2lo[kc], wh, acc2[c], 0, 0, 0);
            acc2[c] = __builtin_amdgcn_mfma_f32_16x16x32_bf16(a2hi[kc], wl, acc2[c], 0, 0, 0);
            acc2[c] = __builtin_amdgcn_mfma_f32_16x16x32_bf16(a2hi[kc], wh, acc2[c], 0, 0, 0);
        }
    }

    __syncthreads();
    // epilogue 2: relu(acc2 + b2) -> LDS, then coalesced fp16 copy-out
    #pragma unroll
    for (int c = 0; c < 8; ++c) {
        int col = c * 16 + rlo;
        float bb = b2[col];
        #pragma unroll
        for (int r = 0; r < 4; ++r) {
            Hs[wave][(quad * 4 + r) * HSTR + col] = fmaxf(acc2[c][r] + bb, 0.f);
        }
    }
    __syncthreads();
    #pragma unroll
    for (int p2 = 0; p2 < 4; ++p2) {
        int r = p2 * 4 + quad;
        int grow = row0 + r;
        if (grow < N_NODES) {
            float4 lo = *(const float4*)&Hs[wave][r * HSTR + rlo * 8];
            float4 hi = *(const float4*)&Hs[wave][r * HSTR + rlo * 8 + 4];
            ushort us[8] = {f2h(lo.x), f2h(lo.y), f2h(lo.z), f2h(lo.w),
                            f2h(hi.x), f2h(hi.y), f2h(hi.z), f2h(hi.w)};
            *(float4*)(Z + (size_t)grow * D + rlo * 8) = *(const float4*)us;
        }
    }

    if (STATS) {
        // per-block column reduction over the 64 rows in Hs (fp32 values)
        int col = tid & 127;
        int half = tid >> 7;
        float s = 0.f, s2 = 0.f;
        #pragma unroll
        for (int i = 0; i < 32; ++i) {
            int row = half * 32 + i;
            if (blk0 + row < N_NODES) {
                float v = Hs[row >> 4][(row & 15) * HSTR + col];
                s += v;
                s2 += v * v;
            }
        }
        red[tid] = s;
        __syncthreads();
        if (half == 0) atomicAdd(&stats[col], s + red[tid + 128]);
        __syncthreads();
        red[tid] = s2;
        __syncthreads();
        if (half == 0) atomicAdd(&stats[D + col], s2 + red[tid + 128]);
    }
}

// ---------------------------------------------------------------------------
// Final: zn = BN(Z)*gamma+beta (fp32 out), p = PReLU(zn @ Wp + bp) (fp32 out)
// Split-bf16 MFMA GEMM with BN folded into the fragment load.
// ---------------------------------------------------------------------------
#define PSTR 132   // floats
__global__ __launch_bounds__(256) void bn_proj(
    const ushort* __restrict__ Z, const float* __restrict__ stats,
    const float* __restrict__ gamma, const float* __restrict__ beta,
    const ushort* __restrict__ Wphi, const ushort* __restrict__ Wplo,
    const float* __restrict__ bp, const float* __restrict__ prelu_a,
    float* __restrict__ zn_out, float* __restrict__ p_out) {
    __shared__ float sc_s[D];
    __shared__ float sh_s[D];
    __shared__ float Ps[4][16 * PSTR];
    int tid = threadIdx.x;
    int lane = tid & 63;
    int wave = tid >> 6;
    int rlo = lane & 15;
    int quad = lane >> 4;

    if (tid < D) {
        float m = stats[tid] * (1.0f / N_NODES);
        float v = stats[D + tid] * (1.0f / N_NODES) - m * m;
        float rs = rsqrtf(v + BN_EPS);
        float sc = rs * gamma[tid];
        sc_s[tid] = sc;
        sh_s[tid] = beta[tid] - m * sc;
    }
    __syncthreads();

    int row0 = blockIdx.x * 64 + wave * 16;
    int arow = row0 + rlo;
    int ar = (arow < N_NODES) ? arow : (N_NODES - 1);

    const bf16x8* Wh = (const bf16x8*)Wphi;
    const bf16x8* Wl = (const bf16x8*)Wplo;

    // load Z frags, apply BN -> zn (fp32 store + split-bf16 a-frags)
    bf16x8 ahi[4], alo[4];
    #pragma unroll
    for (int kc = 0; kc < 4; ++kc) {
        u16x8 raw = *(const u16x8*)(Z + (size_t)ar * D + kc * 32 + quad * 8);
        float zn[8];
        #pragma unroll
        for (int j = 0; j < 8; ++j) {
            int k = kc * 32 + quad * 8 + j;
            zn[j] = sc_s[k] * h2f(raw[j]) + sh_s[k];
            unsigned short h = f2bf(zn[j]);
            ahi[kc][j] = (short)h;
            alo[kc][j] = (short)f2bf(zn[j] - bf2f(h));
        }
        if (arow < N_NODES) {
            float* dst = zn_out + (size_t)arow * D + kc * 32 + quad * 8;
            *(float4*)dst = make_float4(zn[0], zn[1], zn[2], zn[3]);
            *(float4*)(dst + 4) = make_float4(zn[4], zn[5], zn[6], zn[7]);
        }
    }

    f32x4 acc[8];
    #pragma unroll
    for (int c = 0; c < 8; ++c) acc[c] = (f32x4){0.f, 0.f, 0.f, 0.f};
    #pragma unroll
    for (int c = 0; c < 8; ++c) {
        #pragma unroll
        for (int kc = 0; kc < 4; ++kc) {
            bf16x8 wh = Wh[(c * 4 + kc) * 64 + lane];
            bf16x8 wl = Wl[(c * 4 + kc) * 64 + lane];
            acc[c] = __builtin_amdgcn_mfma_f32_16x16x32_bf16(alo[kc], wh, acc[c], 0, 0, 0);
            acc[c] = __builtin_amdgcn_mfma_f32_16x16x32_bf16(ahi[kc], wl, acc[c], 0, 0, 0);
            acc[c] = __builtin_amdgcn_mfma_f32_16x16x32_bf16(ahi[kc], wh, acc[c], 0, 0, 0);
        }
    }

    float aP = prelu_a[0];
    #pragma unroll
    for (int c = 0; c < 8; ++c) {
        int col = c * 16 + rlo;
        float bb = bp[col];
        #pragma unroll
        for (int r = 0; r < 4; ++r) {
            float v = acc[c][r] + bb;
            v = (v >= 0.f) ? v : aP * v;
            Ps[wave][(quad * 4 + r) * PSTR + col] = v;
        }
    }
    __syncthreads();
    #pragma unroll
    for (int p2 = 0; p2 < 8; ++p2) {
        int r = p2 * 2 + (lane >> 5);
        int grow = row0 + r;
        if (grow < N_NODES) {
            *(float4*)(p_out + (size_t)grow * D + (lane & 31) * 4) =
                *(const float4*)&Ps[wave][r * PSTR + (lane & 31) * 4];
        }
    }
}

// ---------------------------------------------------------------------------
extern "C" void kernel_launch(void* const* d_in, const int* in_sizes, int n_in,
                              void* d_out, int out_size, void* d_ws, size_t ws_size,
                              hipStream_t stream) {
    (void)in_sizes; (void)n_in; (void)out_size; (void)ws_size;
    const float* x     = (const float*)d_in[0];
    const float* ew    = (const float*)d_in[1];
    const float* W1s   = (const float*)d_in[2];
    const float* b1s   = (const float*)d_in[3];
    const float* W2s   = (const float*)d_in[4];
    const float* b2s   = (const float*)d_in[5];
    const float* eps   = (const float*)d_in[6];
    const float* gamma = (const float*)d_in[7];
    const float* beta  = (const float*)d_in[8];
    const float* Wp    = (const float*)d_in[9];
    const float* bp    = (const float*)d_in[10];
    const float* pa    = (const float*)d_in[11];
    const int*   ei    = (const int*)d_in[12];
    const int* srcp = ei;
    const int* dstp = ei + N_EDGES;

    // workspace layout (bytes):
    char* wsb = (char*)d_ws;
    float*  stats  = (float*)wsb;                 wsb += 1024;           // 256 f
    int*    offs   = (int*)wsb;                   wsb += 200016;         // 50004 i
    int*    cursor = (int*)wsb;                   wsb += 200016;         // 50004 i
    uint2*  pay    = (uint2*)wsb;                 wsb += 6400000;        // 800000 uint2
    ushort* Wpk    = (ushort*)wsb;                wsb += 14 * 16384 * 2; // split weights
    ushort* Xh     = (ushort*)wsb;                wsb += (size_t)ND * 2; // x in fp16
    ushort* Ah     = (ushort*)wsb;                wsb += (size_t)ND * 2; // gather out fp16
    ushort* Zh     = (ushort*)wsb;                wsb += (size_t)ND * 2; // layer out fp16

    float* out_zn = (float*)d_out;
    float* out_p  = out_zn + ND;

    hipMemsetAsync(stats, 0, 256 * sizeof(float), stream);
    hipMemsetAsync(offs, 0, (N_NODES + 1) * sizeof(int), stream);

    convert_x<<<(ND / 4 + 255) / 256, 256, 0, stream>>>(x, Xh);
    pack_w_split<<<(7 * 16384 + 255) / 256, 256, 0, stream>>>(W1s, W2s, Wp, Wpk);

    hist_kernel<<<(N_EDGES + 255) / 256, 256, 0, stream>>>(dstp, offs);
    scan_kernel<<<1, 1024, 0, stream>>>(offs, cursor);
    fill_kernel<<<(N_EDGES + 255) / 256, 256, 0, stream>>>(srcp, dstp, ew, cursor, pay);

    int mgrid = (N_NODES + 63) / 64;
    const ushort* zin = Xh;
    for (int l = 0; l < 3; ++l) {
        gather_agg_f16<<<(N_NODES * 32 + 255) / 256, 256, 0, stream>>>(zin, offs, pay, eps, l, Ah);
        if (l < 2) {
            mlp_fused<false><<<mgrid, 256, 0, stream>>>(Ah,
                Wpk + (size_t)(2 * l) * 16384,       Wpk + (size_t)(2 * l + 1) * 16384, b1s + (size_t)l * D,
                Wpk + (size_t)(2 * (3 + l)) * 16384, Wpk + (size_t)(2 * (3 + l) + 1) * 16384, b2s + (size_t)l * D,
                Zh, stats);
        } else {
            mlp_fused<true><<<mgrid, 256, 0, stream>>>(Ah,
                Wpk + (size_t)(2 * l) * 16384,       Wpk + (size_t)(2 * l + 1) * 16384, b1s + (size_t)l * D,
                Wpk + (size_t)(2 * (3 + l)) * 16384, Wpk + (size_t)(2 * (3 + l) + 1) * 16384, b2s + (size_t)l * D,
                Zh, stats);
        }
        zin = Zh;
    }
    bn_proj<<<mgrid, 256, 0, stream>>>(Zh, stats, gamma, beta,
        Wpk + (size_t)12 * 16384, Wpk + (size_t)13 * 16384, bp, pa, out_zn, out_p);
}